// Round 5
// baseline (5455.261 us; speedup 1.0000x reference)
//
#include <hip/hip_runtime.h>
#include <hip/hip_bf16.h>

#define N_NODES 100000
#define N_EDGES 1600000

typedef unsigned short u16;
typedef unsigned int u32;

// bf16 <-> f32 as explicit bit ops (RNE)
static __device__ __forceinline__ u16 f2bf(float f) {
    union { float f; u32 u; } v; v.f = f;
    u32 u = v.u;
    u += 0x7FFFu + ((u >> 16) & 1u);   // round-to-nearest-even
    return (u16)(u >> 16);
}
static __device__ __forceinline__ float bf2f(u16 h) {
    union { float f; u32 u; } v; v.u = ((u32)h) << 16; return v.f;
}

// ---------------------------------------------------------------- degrees
__global__ __launch_bounds__(256) void degree_kernel(
    const int* __restrict__ src, const int* __restrict__ dst,
    unsigned* __restrict__ deg_src, unsigned* __restrict__ deg_dst) {
    int i = blockIdx.x * 256 + threadIdx.x;
    if (i < N_EDGES) {
        atomicAdd(&deg_src[src[i]], 1u);
        atomicAdd(&deg_dst[dst[i]], 1u);
    }
}

__global__ __launch_bounds__(256) void norm_kernel(
    const unsigned* __restrict__ deg_src, const unsigned* __restrict__ deg_dst,
    float* __restrict__ norm_src, float* __restrict__ norm_dst) {
    int i = blockIdx.x * 256 + threadIdx.x;
    if (i < N_NODES) {
        unsigned ds = deg_src[i]; if (ds < 1u) ds = 1u;
        unsigned dd = deg_dst[i]; if (dd < 1u) dd = 1u;
        norm_src[i] = rsqrtf((float)ds);
        norm_dst[i] = rsqrtf((float)dd);
    }
}

// ---------------------------------------------------------------- GEMM
// T[n, :DOUT] = bf16( norm_src[n] * (h[n, :DIN] @ W) )
template <int DIN, int DOUT>
__global__ __launch_bounds__(256) void gemm_kernel(
    const float* __restrict__ h, const float* __restrict__ W,
    const float* __restrict__ norm_src, u16* __restrict__ T) {
    constexpr int TM = 64;
    constexpr int KT = 32;
    constexpr int JBLKS = DOUT / 4;
    constexpr int NPT = (TM * DOUT) / (256 * 4);

    __shared__ float hs[KT][TM + 4];
    __shared__ float ws[KT][DOUT];

    const int t = threadIdx.x;
    const int m0 = blockIdx.x * TM;
    const int jblk = t % JBLKS;
    const int nblk = t / JBLKS;
    const int n0 = nblk * NPT;

    float acc[NPT][4];
    for (int i = 0; i < NPT; ++i)
        for (int j = 0; j < 4; ++j) acc[i][j] = 0.f;

    for (int k0 = 0; k0 < DIN; k0 += KT) {
        for (int it = 0; it < 2; ++it) {
            int f = t + it * 256;
            int row = f / (KT / 4);
            int c4  = f % (KT / 4);
            float4 v = make_float4(0.f, 0.f, 0.f, 0.f);
            int gr = m0 + row;
            if (gr < N_NODES)
                v = *reinterpret_cast<const float4*>(&h[gr * DIN + k0 + c4 * 4]);
            hs[c4 * 4 + 0][row] = v.x;
            hs[c4 * 4 + 1][row] = v.y;
            hs[c4 * 4 + 2][row] = v.z;
            hs[c4 * 4 + 3][row] = v.w;
        }
        constexpr int WQ = KT * DOUT / 4;
        constexpr int WITERS = (WQ + 255) / 256;
        for (int it = 0; it < WITERS; ++it) {
            int f = t + it * 256;
            if (f < WQ) {
                int row = f / JBLKS;
                int c4  = f % JBLKS;
                *reinterpret_cast<float4*>(&ws[row][c4 * 4]) =
                    *reinterpret_cast<const float4*>(&W[(k0 + row) * DOUT + c4 * 4]);
            }
        }
        __syncthreads();

#pragma unroll 4
        for (int k = 0; k < KT; ++k) {
            float4 wv = *reinterpret_cast<const float4*>(&ws[k][jblk * 4]);
            float a[NPT];
            if constexpr (NPT % 4 == 0) {
#pragma unroll
                for (int i = 0; i < NPT; i += 4)
                    *reinterpret_cast<float4*>(&a[i]) =
                        *reinterpret_cast<const float4*>(&hs[k][n0 + i]);
            } else if constexpr (NPT == 2) {
                *reinterpret_cast<float2*>(&a[0]) =
                    *reinterpret_cast<const float2*>(&hs[k][n0]);
            } else {
                a[0] = hs[k][n0];
            }
#pragma unroll
            for (int i = 0; i < NPT; ++i) {
                acc[i][0] = fmaf(a[i], wv.x, acc[i][0]);
                acc[i][1] = fmaf(a[i], wv.y, acc[i][1]);
                acc[i][2] = fmaf(a[i], wv.z, acc[i][2]);
                acc[i][3] = fmaf(a[i], wv.w, acc[i][3]);
            }
        }
        __syncthreads();
    }

#pragma unroll
    for (int i = 0; i < NPT; ++i) {
        int n = m0 + n0 + i;
        if (n < N_NODES) {
            float s = norm_src[n];
            ushort4 o;
            o.x = f2bf(acc[i][0] * s);
            o.y = f2bf(acc[i][1] * s);
            o.z = f2bf(acc[i][2] * s);
            o.w = f2bf(acc[i][3] * s);
            *reinterpret_cast<ushort4*>(&T[n * DOUT + jblk * 4]) = o;
        }
    }
}

// ---------------------------------------------------------------- scatter (SpMM via f32 atomics, bf16 gather)
template <int D>
__global__ __launch_bounds__(256) void scatter_kernel(
    const u16* __restrict__ T, const int* __restrict__ src,
    const int* __restrict__ dst, float* __restrict__ agg) {
    constexpr int C4 = D / 4;
    int idx = blockIdx.x * 256 + threadIdx.x;
    int e = idx / C4;
    int c = (idx % C4) * 4;
    if (e < N_EDGES) {
        int s = src[e], d = dst[e];
        ushort4 v = *reinterpret_cast<const ushort4*>(&T[s * D + c]);
        float* ap = &agg[d * D + c];
        atomicAdd(ap + 0, bf2f(v.x));
        atomicAdd(ap + 1, bf2f(v.y));
        atomicAdd(ap + 2, bf2f(v.z));
        atomicAdd(ap + 3, bf2f(v.w));
    }
}

// ---------------------------------------------------------------- finalize in place: agg = relu(agg*norm + b + sb)
template <int D>
__global__ __launch_bounds__(256) void finalize_kernel(
    float* __restrict__ agg, const float* __restrict__ norm_dst,
    const float* __restrict__ b, const float* __restrict__ sb) {
    constexpr int C4 = D / 4;
    int idx = blockIdx.x * 256 + threadIdx.x;
    if (idx < N_NODES * C4) {
        int n = idx / C4;
        int c = (idx % C4) * 4;
        float nd = norm_dst[n];
        float s = sb[0];
        float4 v  = *reinterpret_cast<const float4*>(&agg[n * D + c]);
        float4 bb = *reinterpret_cast<const float4*>(&b[c]);
        float4 o;
        o.x = fmaxf(v.x * nd + bb.x + s, 0.f);
        o.y = fmaxf(v.y * nd + bb.y + s, 0.f);
        o.z = fmaxf(v.z * nd + bb.z + s, 0.f);
        o.w = fmaxf(v.w * nd + bb.w + s, 0.f);
        *reinterpret_cast<float4*>(&agg[n * D + c]) = o;
    }
}

// ---------------------------------------------------------------- last layer: finalize + softmax -> f32 out
__global__ __launch_bounds__(256) void softmax_kernel(
    const float* __restrict__ agg, const float* __restrict__ norm_dst,
    const float* __restrict__ b, const float* __restrict__ sb,
    float* __restrict__ out) {
    int n = blockIdx.x * 256 + threadIdx.x;
    if (n >= N_NODES) return;
    float nd = norm_dst[n];
    float s = sb[0];
    float v[16];
#pragma unroll
    for (int j4 = 0; j4 < 4; ++j4) {
        float4 a  = *reinterpret_cast<const float4*>(&agg[n * 16 + j4 * 4]);
        float4 bb = *reinterpret_cast<const float4*>(&b[j4 * 4]);
        v[j4 * 4 + 0] = fmaxf(a.x * nd + bb.x + s, 0.f);
        v[j4 * 4 + 1] = fmaxf(a.y * nd + bb.y + s, 0.f);
        v[j4 * 4 + 2] = fmaxf(a.z * nd + bb.z + s, 0.f);
        v[j4 * 4 + 3] = fmaxf(a.w * nd + bb.w + s, 0.f);
    }
    float m = v[0];
#pragma unroll
    for (int j = 1; j < 16; ++j) m = fmaxf(m, v[j]);
    float sum = 0.f;
#pragma unroll
    for (int j = 0; j < 16; ++j) { v[j] = __expf(v[j] - m); sum += v[j]; }
    float inv = 1.f / sum;
    float* op = out + n * 16;
#pragma unroll
    for (int j4 = 0; j4 < 4; ++j4) {
        float4 o = make_float4(v[j4 * 4 + 0] * inv, v[j4 * 4 + 1] * inv,
                               v[j4 * 4 + 2] * inv, v[j4 * 4 + 3] * inv);
        *reinterpret_cast<float4*>(op + j4 * 4) = o;
    }
}

// ---------------------------------------------------------------- launch
extern "C" void kernel_launch(void* const* d_in, const int* in_sizes, int n_in,
                              void* d_out, int out_size, void* d_ws, size_t ws_size,
                              hipStream_t stream) {
    const float* x   = (const float*)d_in[0];
    const int*   src = (const int*)d_in[1];
    const int*   dst = (const int*)d_in[2];
    const float* W0 = (const float*)d_in[3];
    const float* b0 = (const float*)d_in[4];
    const float* sb0 = (const float*)d_in[5];
    const float* W1 = (const float*)d_in[6];
    const float* b1 = (const float*)d_in[7];
    const float* sb1 = (const float*)d_in[8];
    const float* W2 = (const float*)d_in[9];
    const float* b2 = (const float*)d_in[10];
    const float* sb2 = (const float*)d_in[11];
    const float* W3 = (const float*)d_in[12];
    const float* b3 = (const float*)d_in[13];
    const float* sb3 = (const float*)d_in[14];

    // workspace layout (78.4 MB):
    //   A    f32  N*128   @ 0          (aggregation + in-place finalized h)
    //   T    bf16 N*128   @ 51,200,000 (transformed features, scatter source)
    //   deg  u32  2*N     @ 76,800,000
    //   norm f32  2*N     @ 77,600,000
    char* ws = (char*)d_ws;
    float*    A        = (float*)ws;
    u16*      T        = (u16*)(ws + 51200000);
    unsigned* deg      = (unsigned*)(ws + 76800000);
    float*    norm_src = (float*)(ws + 77600000);
    float*    norm_dst = norm_src + N_NODES;

    const int EB = (N_EDGES + 255) / 256;
    const int NB = (N_NODES + 255) / 256;
    const int MT = (N_NODES + 63) / 64;

    hipMemsetAsync(deg, 0, 2 * N_NODES * sizeof(unsigned), stream);
    degree_kernel<<<EB, 256, 0, stream>>>(src, dst, deg, deg + N_NODES);
    norm_kernel<<<NB, 256, 0, stream>>>(deg, deg + N_NODES, norm_src, norm_dst);

    // ---- layer 0: 256 -> 128
    gemm_kernel<256, 128><<<MT, 256, 0, stream>>>(x, W0, norm_src, T);
    hipMemsetAsync(A, 0, (size_t)N_NODES * 128 * 4, stream);
    scatter_kernel<128><<<(N_EDGES * 32 + 255) / 256, 256, 0, stream>>>(T, src, dst, A);
    finalize_kernel<128><<<(N_NODES * 32 + 255) / 256, 256, 0, stream>>>(A, norm_dst, b0, sb0);

    // ---- layer 1: 128 -> 64
    gemm_kernel<128, 64><<<MT, 256, 0, stream>>>(A, W1, norm_src, T);
    hipMemsetAsync(A, 0, (size_t)N_NODES * 64 * 4, stream);
    scatter_kernel<64><<<(N_EDGES * 16 + 255) / 256, 256, 0, stream>>>(T, src, dst, A);
    finalize_kernel<64><<<(N_NODES * 16 + 255) / 256, 256, 0, stream>>>(A, norm_dst, b1, sb1);

    // ---- layer 2: 64 -> 32
    gemm_kernel<64, 32><<<MT, 256, 0, stream>>>(A, W2, norm_src, T);
    hipMemsetAsync(A, 0, (size_t)N_NODES * 32 * 4, stream);
    scatter_kernel<32><<<(N_EDGES * 8 + 255) / 256, 256, 0, stream>>>(T, src, dst, A);
    finalize_kernel<32><<<(N_NODES * 8 + 255) / 256, 256, 0, stream>>>(A, norm_dst, b2, sb2);

    // ---- layer 3: 32 -> 16 + softmax -> f32 out
    gemm_kernel<32, 16><<<MT, 256, 0, stream>>>(A, W3, norm_src, T);
    hipMemsetAsync(A, 0, (size_t)N_NODES * 16 * 4, stream);
    scatter_kernel<16><<<(N_EDGES * 4 + 255) / 256, 256, 0, stream>>>(T, src, dst, A);
    softmax_kernel<<<NB, 256, 0, stream>>>(A, norm_dst, b3, sb3, (float*)d_out);
}

// Round 6
// 681.956 us; speedup vs baseline: 7.9994x; 7.9994x over previous
//
#include <hip/hip_runtime.h>
#include <hip/hip_bf16.h>

#define N_NODES 100000
#define N_EDGES 1600000

typedef unsigned short u16;
typedef unsigned int u32;

// bf16 <-> f32 as explicit bit ops (RNE)
static __device__ __forceinline__ u16 f2bf(float f) {
    union { float f; u32 u; } v; v.f = f;
    u32 u = v.u;
    u += 0x7FFFu + ((u >> 16) & 1u);
    return (u16)(u >> 16);
}
static __device__ __forceinline__ float bf2f(u16 h) {
    union { float f; u32 u; } v; v.u = ((u32)h) << 16; return v.f;
}

// ---------------------------------------------------------------- degrees (src out-degree, dst in-degree)
__global__ __launch_bounds__(256) void degree_kernel(
    const int* __restrict__ src, const int* __restrict__ dst,
    u32* __restrict__ deg_src, u32* __restrict__ indeg) {
    int i = blockIdx.x * 256 + threadIdx.x;
    if (i < N_EDGES) {
        atomicAdd(&deg_src[src[i]], 1u);
        atomicAdd(&indeg[dst[i]], 1u);
    }
}

__global__ __launch_bounds__(256) void norm_kernel(
    const u32* __restrict__ deg_src, const u32* __restrict__ indeg,
    float* __restrict__ norm_src, float* __restrict__ norm_dst) {
    int i = blockIdx.x * 256 + threadIdx.x;
    if (i < N_NODES) {
        u32 ds = deg_src[i]; if (ds < 1u) ds = 1u;
        u32 dd = indeg[i];   if (dd < 1u) dd = 1u;
        norm_src[i] = rsqrtf((float)ds);
        norm_dst[i] = rsqrtf((float)dd);
    }
}

// ---------------------------------------------------------------- exclusive scan of indeg -> row_ptr (2-level)
#define SCAN_B 512
#define SCAN_NBLK ((N_NODES + SCAN_B - 1) / SCAN_B)   // 196

__global__ __launch_bounds__(SCAN_B) void scan1_kernel(
    const u32* __restrict__ indeg, u32* __restrict__ row_ptr, u32* __restrict__ bsum) {
    __shared__ u32 s[SCAN_B];
    int t = threadIdx.x;
    int gid = blockIdx.x * SCAN_B + t;
    u32 v = (gid < N_NODES) ? indeg[gid] : 0u;
    s[t] = v;
    __syncthreads();
    for (int off = 1; off < SCAN_B; off <<= 1) {
        u32 x = (t >= off) ? s[t - off] : 0u;
        __syncthreads();
        s[t] += x;
        __syncthreads();
    }
    if (gid < N_NODES) row_ptr[gid + 1] = s[t];   // inclusive partial
    if (t == SCAN_B - 1) bsum[blockIdx.x] = s[t];
}

__global__ __launch_bounds__(256) void scan2_kernel(u32* __restrict__ bsum, u32* __restrict__ boff) {
    __shared__ u32 s[256];
    int t = threadIdx.x;
    s[t] = (t < SCAN_NBLK) ? bsum[t] : 0u;
    __syncthreads();
    for (int off = 1; off < 256; off <<= 1) {
        u32 x = (t >= off) ? s[t - off] : 0u;
        __syncthreads();
        s[t] += x;
        __syncthreads();
    }
    if (t < SCAN_NBLK) boff[t] = (t == 0) ? 0u : s[t - 1];   // exclusive
}

__global__ __launch_bounds__(256) void scan3_kernel(u32* __restrict__ row_ptr, const u32* __restrict__ boff) {
    int gid = blockIdx.x * 256 + threadIdx.x;
    if (gid < N_NODES) {
        row_ptr[gid + 1] += boff[gid / SCAN_B];
        if (gid == 0) row_ptr[0] = 0u;
    }
}

// ---------------------------------------------------------------- CSR fill: col[] = src sorted by dst
__global__ __launch_bounds__(256) void fill_kernel(
    const int* __restrict__ src, const int* __restrict__ dst,
    const u32* __restrict__ row_ptr, u32* __restrict__ cursor, u32* __restrict__ col) {
    int e = blockIdx.x * 256 + threadIdx.x;
    if (e < N_EDGES) {
        int d = dst[e];
        u32 pos = row_ptr[d] + atomicAdd(&cursor[d], 1u);
        col[pos] = (u32)src[e];
    }
}

// ---------------------------------------------------------------- GEMM: T[n,:] = bf16(norm_src[n] * (h[n,:] @ W))
template <int DIN, int DOUT>
__global__ __launch_bounds__(256) void gemm_kernel(
    const float* __restrict__ h, const float* __restrict__ W,
    const float* __restrict__ norm_src, u16* __restrict__ T) {
    constexpr int TM = 64;
    constexpr int KT = 32;
    constexpr int JBLKS = DOUT / 4;
    constexpr int NPT = (TM * DOUT) / (256 * 4);

    __shared__ float hs[KT][TM + 4];
    __shared__ float ws[KT][DOUT];

    const int t = threadIdx.x;
    const int m0 = blockIdx.x * TM;
    const int jblk = t % JBLKS;
    const int nblk = t / JBLKS;
    const int n0 = nblk * NPT;

    float acc[NPT][4];
    for (int i = 0; i < NPT; ++i)
        for (int j = 0; j < 4; ++j) acc[i][j] = 0.f;

    for (int k0 = 0; k0 < DIN; k0 += KT) {
        for (int it = 0; it < 2; ++it) {
            int f = t + it * 256;
            int row = f / (KT / 4);
            int c4  = f % (KT / 4);
            float4 v = make_float4(0.f, 0.f, 0.f, 0.f);
            int gr = m0 + row;
            if (gr < N_NODES)
                v = *reinterpret_cast<const float4*>(&h[gr * DIN + k0 + c4 * 4]);
            hs[c4 * 4 + 0][row] = v.x;
            hs[c4 * 4 + 1][row] = v.y;
            hs[c4 * 4 + 2][row] = v.z;
            hs[c4 * 4 + 3][row] = v.w;
        }
        constexpr int WQ = KT * DOUT / 4;
        constexpr int WITERS = (WQ + 255) / 256;
        for (int it = 0; it < WITERS; ++it) {
            int f = t + it * 256;
            if (f < WQ) {
                int row = f / JBLKS;
                int c4  = f % JBLKS;
                *reinterpret_cast<float4*>(&ws[row][c4 * 4]) =
                    *reinterpret_cast<const float4*>(&W[(k0 + row) * DOUT + c4 * 4]);
            }
        }
        __syncthreads();

#pragma unroll 4
        for (int k = 0; k < KT; ++k) {
            float4 wv = *reinterpret_cast<const float4*>(&ws[k][jblk * 4]);
            float a[NPT];
            if constexpr (NPT % 4 == 0) {
#pragma unroll
                for (int i = 0; i < NPT; i += 4)
                    *reinterpret_cast<float4*>(&a[i]) =
                        *reinterpret_cast<const float4*>(&hs[k][n0 + i]);
            } else if constexpr (NPT == 2) {
                *reinterpret_cast<float2*>(&a[0]) =
                    *reinterpret_cast<const float2*>(&hs[k][n0]);
            } else {
                a[0] = hs[k][n0];
            }
#pragma unroll
            for (int i = 0; i < NPT; ++i) {
                acc[i][0] = fmaf(a[i], wv.x, acc[i][0]);
                acc[i][1] = fmaf(a[i], wv.y, acc[i][1]);
                acc[i][2] = fmaf(a[i], wv.z, acc[i][2]);
                acc[i][3] = fmaf(a[i], wv.w, acc[i][3]);
            }
        }
        __syncthreads();
    }

#pragma unroll
    for (int i = 0; i < NPT; ++i) {
        int n = m0 + n0 + i;
        if (n < N_NODES) {
            float s = norm_src[n];
            ushort4 o;
            o.x = f2bf(acc[i][0] * s);
            o.y = f2bf(acc[i][1] * s);
            o.z = f2bf(acc[i][2] * s);
            o.w = f2bf(acc[i][3] * s);
            *reinterpret_cast<ushort4*>(&T[n * DOUT + jblk * 4]) = o;
        }
    }
}

// ---------------------------------------------------------------- pull aggregation + fused finalize
// h[n,:] = relu( (sum_{e in in(n)} T[col[e],:]) * norm_dst[n] + b + sb )
// D/4 threads per node, each owns 4 features; edge loop 2-way unrolled.
template <int D>
__global__ __launch_bounds__(256) void pull_kernel(
    const u16* __restrict__ T, const u32* __restrict__ row_ptr,
    const u32* __restrict__ col, const float* __restrict__ norm_dst,
    const float* __restrict__ b, const float* __restrict__ sb,
    float* __restrict__ h) {
    constexpr int TPN = D / 4;
    int tid = blockIdx.x * 256 + threadIdx.x;
    int n = tid / TPN;
    int c = (tid % TPN) * 4;
    if (n >= N_NODES) return;

    u32 beg = row_ptr[n], end = row_ptr[n + 1];
    float a0 = 0.f, a1 = 0.f, a2 = 0.f, a3 = 0.f;

    u32 e = beg;
    for (; e + 1 < end; e += 2) {
        u32 s0 = col[e], s1 = col[e + 1];
        ushort4 v0 = *reinterpret_cast<const ushort4*>(&T[s0 * D + c]);
        ushort4 v1 = *reinterpret_cast<const ushort4*>(&T[s1 * D + c]);
        a0 += bf2f(v0.x) + bf2f(v1.x);
        a1 += bf2f(v0.y) + bf2f(v1.y);
        a2 += bf2f(v0.z) + bf2f(v1.z);
        a3 += bf2f(v0.w) + bf2f(v1.w);
    }
    if (e < end) {
        u32 s0 = col[e];
        ushort4 v0 = *reinterpret_cast<const ushort4*>(&T[s0 * D + c]);
        a0 += bf2f(v0.x); a1 += bf2f(v0.y); a2 += bf2f(v0.z); a3 += bf2f(v0.w);
    }

    float nd = norm_dst[n];
    float sv = sb[0];
    float4 bb = *reinterpret_cast<const float4*>(&b[c]);
    float4 o;
    o.x = fmaxf(a0 * nd + bb.x + sv, 0.f);
    o.y = fmaxf(a1 * nd + bb.y + sv, 0.f);
    o.z = fmaxf(a2 * nd + bb.z + sv, 0.f);
    o.w = fmaxf(a3 * nd + bb.w + sv, 0.f);
    *reinterpret_cast<float4*>(&h[n * D + c]) = o;
}

// ---------------------------------------------------------------- softmax over 16 finalized values -> f32 out
__global__ __launch_bounds__(256) void softmax_kernel(
    const float* __restrict__ h, float* __restrict__ out) {
    int n = blockIdx.x * 256 + threadIdx.x;
    if (n >= N_NODES) return;
    float v[16];
#pragma unroll
    for (int j4 = 0; j4 < 4; ++j4) {
        float4 a = *reinterpret_cast<const float4*>(&h[n * 16 + j4 * 4]);
        v[j4 * 4 + 0] = a.x; v[j4 * 4 + 1] = a.y;
        v[j4 * 4 + 2] = a.z; v[j4 * 4 + 3] = a.w;
    }
    float m = v[0];
#pragma unroll
    for (int j = 1; j < 16; ++j) m = fmaxf(m, v[j]);
    float sum = 0.f;
#pragma unroll
    for (int j = 0; j < 16; ++j) { v[j] = __expf(v[j] - m); sum += v[j]; }
    float inv = 1.f / sum;
    float* op = out + n * 16;
#pragma unroll
    for (int j4 = 0; j4 < 4; ++j4) {
        float4 o = make_float4(v[j4 * 4 + 0] * inv, v[j4 * 4 + 1] * inv,
                               v[j4 * 4 + 2] * inv, v[j4 * 4 + 3] * inv);
        *reinterpret_cast<float4*>(op + j4 * 4) = o;
    }
}

// ---------------------------------------------------------------- launch
extern "C" void kernel_launch(void* const* d_in, const int* in_sizes, int n_in,
                              void* d_out, int out_size, void* d_ws, size_t ws_size,
                              hipStream_t stream) {
    const float* x   = (const float*)d_in[0];
    const int*   src = (const int*)d_in[1];
    const int*   dst = (const int*)d_in[2];
    const float* W0 = (const float*)d_in[3];
    const float* b0 = (const float*)d_in[4];
    const float* sb0 = (const float*)d_in[5];
    const float* W1 = (const float*)d_in[6];
    const float* b1 = (const float*)d_in[7];
    const float* sb1 = (const float*)d_in[8];
    const float* W2 = (const float*)d_in[9];
    const float* b2 = (const float*)d_in[10];
    const float* sb2 = (const float*)d_in[11];
    const float* W3 = (const float*)d_in[12];
    const float* b3 = (const float*)d_in[13];
    const float* sb3 = (const float*)d_in[14];

    // workspace layout (~85.2 MB):
    char* ws = (char*)d_ws;
    float* h        = (float*)ws;                       // f32 N*128      @ 0
    u16*   T        = (u16*)(ws + 51200000);            // bf16 N*128     @ 51.2M
    u32*   col      = (u32*)(ws + 76800000);            // u32 E          @ 76.8M
    u32*   row_ptr  = (u32*)(ws + 83200000);            // u32 N+1        @ 83.2M
    u32*   cursor   = (u32*)(ws + 83600016);            // u32 N
    u32*   deg_src  = (u32*)(ws + 84000016);            // u32 N
    u32*   indeg    = (u32*)(ws + 84400016);            // u32 N
    float* norm_src = (float*)(ws + 84800016);          // f32 N
    float* norm_dst = (float*)(ws + 85200016);          // f32 N
    u32*   bsum     = (u32*)(ws + 85600016);            // u32 SCAN_NBLK
    u32*   boff     = (u32*)(ws + 85602064);            // u32 SCAN_NBLK

    const int EB = (N_EDGES + 255) / 256;
    const int NB = (N_NODES + 255) / 256;
    const int MT = (N_NODES + 63) / 64;

    // ---- CSR build + norms
    hipMemsetAsync(deg_src, 0, N_NODES * 4, stream);
    hipMemsetAsync(indeg,   0, N_NODES * 4, stream);
    hipMemsetAsync(cursor,  0, N_NODES * 4, stream);
    degree_kernel<<<EB, 256, 0, stream>>>(src, dst, deg_src, indeg);
    scan1_kernel<<<SCAN_NBLK, SCAN_B, 0, stream>>>(indeg, row_ptr, bsum);
    scan2_kernel<<<1, 256, 0, stream>>>(bsum, boff);
    scan3_kernel<<<NB, 256, 0, stream>>>(row_ptr, boff);
    norm_kernel<<<NB, 256, 0, stream>>>(deg_src, indeg, norm_src, norm_dst);
    fill_kernel<<<EB, 256, 0, stream>>>(src, dst, row_ptr, cursor, col);

    // ---- layer 0: 256 -> 128
    gemm_kernel<256, 128><<<MT, 256, 0, stream>>>(x, W0, norm_src, T);
    pull_kernel<128><<<(N_NODES * 32 + 255) / 256, 256, 0, stream>>>(T, row_ptr, col, norm_dst, b0, sb0, h);

    // ---- layer 1: 128 -> 64
    gemm_kernel<128, 64><<<MT, 256, 0, stream>>>(h, W1, norm_src, T);
    pull_kernel<64><<<(N_NODES * 16 + 255) / 256, 256, 0, stream>>>(T, row_ptr, col, norm_dst, b1, sb1, h);

    // ---- layer 2: 64 -> 32
    gemm_kernel<64, 32><<<MT, 256, 0, stream>>>(h, W2, norm_src, T);
    pull_kernel<32><<<(N_NODES * 8 + 255) / 256, 256, 0, stream>>>(T, row_ptr, col, norm_dst, b2, sb2, h);

    // ---- layer 3: 32 -> 16 + softmax
    gemm_kernel<32, 16><<<MT, 256, 0, stream>>>(h, W3, norm_src, T);
    pull_kernel<16><<<(N_NODES * 4 + 255) / 256, 256, 0, stream>>>(T, row_ptr, col, norm_dst, b3, sb3, h);
    softmax_kernel<<<NB, 256, 0, stream>>>(h, (float*)d_out);
}

// Round 8
// 646.623 us; speedup vs baseline: 8.4365x; 1.0546x over previous
//
#include <hip/hip_runtime.h>
#include <hip/hip_bf16.h>

#define N_NODES 100000
#define N_EDGES 1600000
#define NSHARD 4

typedef unsigned short u16;
typedef unsigned int u32;

// bf16 <-> f32 as explicit bit ops (RNE)
static __device__ __forceinline__ u16 f2bf(float f) {
    union { float f; u32 u; } v; v.f = f;
    u32 u = v.u;
    u += 0x7FFFu + ((u >> 16) & 1u);
    return (u16)(u >> 16);
}
static __device__ __forceinline__ float bf2f(u16 h) {
    union { float f; u32 u; } v; v.u = ((u32)h) << 16; return v.f;
}

// ---------------------------------------------------------------- degrees, sharded; store per-edge shard-local rank
__global__ __launch_bounds__(256) void degree_kernel(
    const int* __restrict__ src, const int* __restrict__ dst,
    u32* __restrict__ shist, u32* __restrict__ dhist, u32* __restrict__ pos) {
    int e = blockIdx.x * 256 + threadIdx.x;
    if (e < N_EDGES) {
        int sh = threadIdx.x >> 6;          // wave id in block -> shard
        atomicAdd(&shist[sh * N_NODES + src[e]], 1u);
        pos[e] = atomicAdd(&dhist[sh * N_NODES + dst[e]], 1u);
    }
}

// ---------------------------------------------------------------- reduce shards -> indeg, norms, shard base offsets
__global__ __launch_bounds__(256) void csr_prep_kernel(
    u32* __restrict__ dhist, const u32* __restrict__ shist,
    u32* __restrict__ indeg, float* __restrict__ norm_src, float* __restrict__ norm_dst) {
    int n = blockIdx.x * 256 + threadIdx.x;
    if (n >= N_NODES) return;
    u32 d0 = dhist[n], d1 = dhist[N_NODES + n], d2 = dhist[2 * N_NODES + n], d3 = dhist[3 * N_NODES + n];
    u32 s0 = shist[n], s1 = shist[N_NODES + n], s2 = shist[2 * N_NODES + n], s3 = shist[3 * N_NODES + n];
    u32 id = d0 + d1 + d2 + d3;
    u32 od = s0 + s1 + s2 + s3;
    indeg[n] = id;
    norm_dst[n] = rsqrtf((float)(id < 1u ? 1u : id));
    norm_src[n] = rsqrtf((float)(od < 1u ? 1u : od));
    // exclusive shard bases (overwrite dhist in place)
    dhist[n] = 0u;
    dhist[N_NODES + n] = d0;
    dhist[2 * N_NODES + n] = d0 + d1;
    dhist[3 * N_NODES + n] = d0 + d1 + d2;
}

// ---------------------------------------------------------------- exclusive scan of indeg -> row_ptr (2-level)
#define SCAN_B 512
#define SCAN_NBLK ((N_NODES + SCAN_B - 1) / SCAN_B)   // 196

__global__ __launch_bounds__(SCAN_B) void scan1_kernel(
    const u32* __restrict__ indeg, u32* __restrict__ row_ptr, u32* __restrict__ bsum) {
    __shared__ u32 s[SCAN_B];
    int t = threadIdx.x;
    int gid = blockIdx.x * SCAN_B + t;
    u32 v = (gid < N_NODES) ? indeg[gid] : 0u;
    s[t] = v;
    __syncthreads();
    for (int off = 1; off < SCAN_B; off <<= 1) {
        u32 x = (t >= off) ? s[t - off] : 0u;
        __syncthreads();
        s[t] += x;
        __syncthreads();
    }
    if (gid < N_NODES) row_ptr[gid + 1] = s[t];   // inclusive partial
    if (t == SCAN_B - 1) bsum[blockIdx.x] = s[t];
}

__global__ __launch_bounds__(256) void scan2_kernel(u32* __restrict__ bsum, u32* __restrict__ boff) {
    __shared__ u32 s[256];
    int t = threadIdx.x;
    s[t] = (t < SCAN_NBLK) ? bsum[t] : 0u;
    __syncthreads();
    for (int off = 1; off < 256; off <<= 1) {
        u32 x = (t >= off) ? s[t - off] : 0u;
        __syncthreads();
        s[t] += x;
        __syncthreads();
    }
    if (t < SCAN_NBLK) boff[t] = (t == 0) ? 0u : s[t - 1];   // exclusive
}

__global__ __launch_bounds__(256) void scan3_kernel(u32* __restrict__ row_ptr, const u32* __restrict__ boff) {
    int gid = blockIdx.x * 256 + threadIdx.x;
    if (gid < N_NODES) {
        row_ptr[gid + 1] += boff[gid / SCAN_B];
        if (gid == 0) row_ptr[0] = 0u;
    }
}

// ---------------------------------------------------------------- CSR fill, atomic-free
__global__ __launch_bounds__(256) void fill_kernel(
    const int* __restrict__ src, const int* __restrict__ dst,
    const u32* __restrict__ row_ptr, const u32* __restrict__ base,
    const u32* __restrict__ pos, u32* __restrict__ col) {
    int e = blockIdx.x * 256 + threadIdx.x;
    if (e < N_EDGES) {
        int d = dst[e];
        int sh = threadIdx.x >> 6;          // must match degree_kernel's mapping
        u32 p = row_ptr[d] + base[sh * N_NODES + d] + pos[e];
        col[p] = (u32)src[e];
    }
}

// ---------------------------------------------------------------- GEMM: T[n,:] = bf16(norm_src[n] * (h[n,:] @ W))
template <int DIN, int DOUT>
__global__ __launch_bounds__(256) void gemm_kernel(
    const float* __restrict__ h, const float* __restrict__ W,
    const float* __restrict__ norm_src, u16* __restrict__ T) {
    constexpr int TM = 64;
    constexpr int KT = 32;
    constexpr int JBLKS = DOUT / 4;
    constexpr int NPT = (TM * DOUT) / (256 * 4);

    __shared__ float hs[KT][TM + 4];
    __shared__ float ws[KT][DOUT];

    const int t = threadIdx.x;
    const int m0 = blockIdx.x * TM;
    const int jblk = t % JBLKS;
    const int nblk = t / JBLKS;
    const int n0 = nblk * NPT;

    float acc[NPT][4];
    for (int i = 0; i < NPT; ++i)
        for (int j = 0; j < 4; ++j) acc[i][j] = 0.f;

    for (int k0 = 0; k0 < DIN; k0 += KT) {
        for (int it = 0; it < 2; ++it) {
            int f = t + it * 256;
            int row = f / (KT / 4);
            int c4  = f % (KT / 4);
            float4 v = make_float4(0.f, 0.f, 0.f, 0.f);
            int gr = m0 + row;
            if (gr < N_NODES)
                v = *reinterpret_cast<const float4*>(&h[gr * DIN + k0 + c4 * 4]);
            hs[c4 * 4 + 0][row] = v.x;
            hs[c4 * 4 + 1][row] = v.y;
            hs[c4 * 4 + 2][row] = v.z;
            hs[c4 * 4 + 3][row] = v.w;
        }
        constexpr int WQ = KT * DOUT / 4;
        constexpr int WITERS = (WQ + 255) / 256;
        for (int it = 0; it < WITERS; ++it) {
            int f = t + it * 256;
            if (f < WQ) {
                int row = f / JBLKS;
                int c4  = f % JBLKS;
                *reinterpret_cast<float4*>(&ws[row][c4 * 4]) =
                    *reinterpret_cast<const float4*>(&W[(k0 + row) * DOUT + c4 * 4]);
            }
        }
        __syncthreads();

#pragma unroll 4
        for (int k = 0; k < KT; ++k) {
            float4 wv = *reinterpret_cast<const float4*>(&ws[k][jblk * 4]);
            float a[NPT];
            if constexpr (NPT % 4 == 0) {
#pragma unroll
                for (int i = 0; i < NPT; i += 4)
                    *reinterpret_cast<float4*>(&a[i]) =
                        *reinterpret_cast<const float4*>(&hs[k][n0 + i]);
            } else if constexpr (NPT == 2) {
                *reinterpret_cast<float2*>(&a[0]) =
                    *reinterpret_cast<const float2*>(&hs[k][n0]);
            } else {
                a[0] = hs[k][n0];
            }
#pragma unroll
            for (int i = 0; i < NPT; ++i) {
                acc[i][0] = fmaf(a[i], wv.x, acc[i][0]);
                acc[i][1] = fmaf(a[i], wv.y, acc[i][1]);
                acc[i][2] = fmaf(a[i], wv.z, acc[i][2]);
                acc[i][3] = fmaf(a[i], wv.w, acc[i][3]);
            }
        }
        __syncthreads();
    }

#pragma unroll
    for (int i = 0; i < NPT; ++i) {
        int n = m0 + n0 + i;
        if (n < N_NODES) {
            float s = norm_src[n];
            ushort4 o;
            o.x = f2bf(acc[i][0] * s);
            o.y = f2bf(acc[i][1] * s);
            o.z = f2bf(acc[i][2] * s);
            o.w = f2bf(acc[i][3] * s);
            *reinterpret_cast<ushort4*>(&T[n * DOUT + jblk * 4]) = o;
        }
    }
}

// ---------------------------------------------------------------- pull aggregation + fused finalize
template <int D>
__global__ __launch_bounds__(256) void pull_kernel(
    const u16* __restrict__ T, const u32* __restrict__ row_ptr,
    const u32* __restrict__ col, const float* __restrict__ norm_dst,
    const float* __restrict__ b, const float* __restrict__ sb,
    float* __restrict__ h) {
    constexpr int TPN = D / 4;
    int tid = blockIdx.x * 256 + threadIdx.x;
    int n = tid / TPN;
    int c = (tid % TPN) * 4;
    if (n >= N_NODES) return;

    u32 beg = row_ptr[n], end = row_ptr[n + 1];
    float a0 = 0.f, a1 = 0.f, a2 = 0.f, a3 = 0.f;

    u32 e = beg;
    for (; e + 1 < end; e += 2) {
        u32 s0 = col[e], s1 = col[e + 1];
        ushort4 v0 = *reinterpret_cast<const ushort4*>(&T[s0 * D + c]);
        ushort4 v1 = *reinterpret_cast<const ushort4*>(&T[s1 * D + c]);
        a0 += bf2f(v0.x) + bf2f(v1.x);
        a1 += bf2f(v0.y) + bf2f(v1.y);
        a2 += bf2f(v0.z) + bf2f(v1.z);
        a3 += bf2f(v0.w) + bf2f(v1.w);
    }
    if (e < end) {
        u32 s0 = col[e];
        ushort4 v0 = *reinterpret_cast<const ushort4*>(&T[s0 * D + c]);
        a0 += bf2f(v0.x); a1 += bf2f(v0.y); a2 += bf2f(v0.z); a3 += bf2f(v0.w);
    }

    float nd = norm_dst[n];
    float sv = sb[0];
    float4 bb = *reinterpret_cast<const float4*>(&b[c]);
    float4 o;
    o.x = fmaxf(a0 * nd + bb.x + sv, 0.f);
    o.y = fmaxf(a1 * nd + bb.y + sv, 0.f);
    o.z = fmaxf(a2 * nd + bb.z + sv, 0.f);
    o.w = fmaxf(a3 * nd + bb.w + sv, 0.f);
    *reinterpret_cast<float4*>(&h[n * D + c]) = o;
}

// ---------------------------------------------------------------- softmax over 16 finalized values -> f32 out
__global__ __launch_bounds__(256) void softmax_kernel(
    const float* __restrict__ h, float* __restrict__ out) {
    int n = blockIdx.x * 256 + threadIdx.x;
    if (n >= N_NODES) return;
    float v[16];
#pragma unroll
    for (int j4 = 0; j4 < 4; ++j4) {
        float4 a = *reinterpret_cast<const float4*>(&h[n * 16 + j4 * 4]);
        v[j4 * 4 + 0] = a.x; v[j4 * 4 + 1] = a.y;
        v[j4 * 4 + 2] = a.z; v[j4 * 4 + 3] = a.w;
    }
    float m = v[0];
#pragma unroll
    for (int j = 1; j < 16; ++j) m = fmaxf(m, v[j]);
    float sum = 0.f;
#pragma unroll
    for (int j = 0; j < 16; ++j) { v[j] = __expf(v[j] - m); sum += v[j]; }
    float inv = 1.f / sum;
    float* op = out + n * 16;
#pragma unroll
    for (int j4 = 0; j4 < 4; ++j4) {
        float4 o = make_float4(v[j4 * 4 + 0] * inv, v[j4 * 4 + 1] * inv,
                               v[j4 * 4 + 2] * inv, v[j4 * 4 + 3] * inv);
        *reinterpret_cast<float4*>(op + j4 * 4) = o;
    }
}

// ---------------------------------------------------------------- launch
extern "C" void kernel_launch(void* const* d_in, const int* in_sizes, int n_in,
                              void* d_out, int out_size, void* d_ws, size_t ws_size,
                              hipStream_t stream) {
    const float* x   = (const float*)d_in[0];
    const int*   src = (const int*)d_in[1];
    const int*   dst = (const int*)d_in[2];
    const float* W0 = (const float*)d_in[3];
    const float* b0 = (const float*)d_in[4];
    const float* sb0 = (const float*)d_in[5];
    const float* W1 = (const float*)d_in[6];
    const float* b1 = (const float*)d_in[7];
    const float* sb1 = (const float*)d_in[8];
    const float* W2 = (const float*)d_in[9];
    const float* b2 = (const float*)d_in[10];
    const float* sb2 = (const float*)d_in[11];
    const float* W3 = (const float*)d_in[12];
    const float* b3 = (const float*)d_in[13];
    const float* sb3 = (const float*)d_in[14];

    // workspace layout (peak 84.81 MB; proven-safe budget 85.6 MB):
    //   h    f32  N*128        @ 0
    //   T    bf16 N*128        @ 51.2M   — during CSR build this region holds:
    //        dhist u32 4*N     @ T+0        (shard in-deg counts -> shard bases)
    //        shist u32 4*N     @ T+1.6M     (shard out-deg counts)
    //        pos   u32 E       @ T+3.2M     (per-edge shard-local rank)
    //   col  u32  E            @ 76.8M
    //   row_ptr u32 N+1        @ 83.2M
    //   norm_src f32 N         @ 83,600,016
    //   norm_dst f32 N         @ 84,000,016
    //   bsum/boff u32          @ 84,400,016
    //   indeg u32 N            @ 84,408,016
    char* ws = (char*)d_ws;
    float* h        = (float*)ws;
    u16*   T        = (u16*)(ws + 51200000);
    u32*   dhist    = (u32*)(ws + 51200000);
    u32*   shist    = (u32*)(ws + 51200000 + 1600000);
    u32*   pos      = (u32*)(ws + 51200000 + 3200000);
    u32*   col      = (u32*)(ws + 76800000);
    u32*   row_ptr  = (u32*)(ws + 83200000);
    float* norm_src = (float*)(ws + 83600016);
    float* norm_dst = (float*)(ws + 84000016);
    u32*   bsum     = (u32*)(ws + 84400016);
    u32*   boff     = (u32*)(ws + 84404016);
    u32*   indeg    = (u32*)(ws + 84408016);

    const int EB = (N_EDGES + 255) / 256;
    const int NB = (N_NODES + 255) / 256;
    const int MT = (N_NODES + 63) / 64;

    // ---- CSR build + norms (atomic-light)
    hipMemsetAsync(dhist, 0, 2 * NSHARD * N_NODES * 4, stream);   // dhist + shist contiguous
    degree_kernel<<<EB, 256, 0, stream>>>(src, dst, shist, dhist, pos);
    csr_prep_kernel<<<NB, 256, 0, stream>>>(dhist, shist, indeg, norm_src, norm_dst);
    scan1_kernel<<<SCAN_NBLK, SCAN_B, 0, stream>>>(indeg, row_ptr, bsum);
    scan2_kernel<<<1, 256, 0, stream>>>(bsum, boff);
    scan3_kernel<<<NB, 256, 0, stream>>>(row_ptr, boff);
    fill_kernel<<<EB, 256, 0, stream>>>(src, dst, row_ptr, dhist, pos, col);

    // ---- layer 0: 256 -> 128
    gemm_kernel<256, 128><<<MT, 256, 0, stream>>>(x, W0, norm_src, T);
    pull_kernel<128><<<(N_NODES * 32 + 255) / 256, 256, 0, stream>>>(T, row_ptr, col, norm_dst, b0, sb0, h);

    // ---- layer 1: 128 -> 64
    gemm_kernel<128, 64><<<MT, 256, 0, stream>>>(h, W1, norm_src, T);
    pull_kernel<64><<<(N_NODES * 16 + 255) / 256, 256, 0, stream>>>(T, row_ptr, col, norm_dst, b1, sb1, h);

    // ---- layer 2: 64 -> 32
    gemm_kernel<64, 32><<<MT, 256, 0, stream>>>(h, W2, norm_src, T);
    pull_kernel<32><<<(N_NODES * 8 + 255) / 256, 256, 0, stream>>>(T, row_ptr, col, norm_dst, b2, sb2, h);

    // ---- layer 3: 32 -> 16 + softmax
    gemm_kernel<32, 16><<<MT, 256, 0, stream>>>(h, W3, norm_src, T);
    pull_kernel<16><<<(N_NODES * 4 + 255) / 256, 256, 0, stream>>>(T, row_ptr, col, norm_dst, b3, sb3, h);
    softmax_kernel<<<NB, 256, 0, stream>>>(h, (float*)d_out);
}

// Round 10
// 617.299 us; speedup vs baseline: 8.8373x; 1.0475x over previous
//
#include <hip/hip_runtime.h>
#include <hip/hip_bf16.h>

#define N_NODES 100000
#define N_EDGES 1600000

typedef unsigned short u16;
typedef unsigned int u32;

// bf16 -> f32 expansion (exact) and f32 -> bf16 (RNE)
static __device__ __forceinline__ u16 f2bf(float f) {
    union { float f; u32 u; } v; v.f = f;
    u32 u = v.u;
    u += 0x7FFFu + ((u >> 16) & 1u);
    return (u16)(u >> 16);
}
static __device__ __forceinline__ float bflo(u32 w) {
    union { u32 u; float f; } v; v.u = w << 16; return v.f;
}
static __device__ __forceinline__ float bfhi(u32 w) {
    union { u32 u; float f; } v; v.u = w & 0xFFFF0000u; return v.f;
}

// ---------------------------------------------------------------- degrees + per-edge rank (single shard)
__global__ __launch_bounds__(256) void degree_kernel(
    const int* __restrict__ src, const int* __restrict__ dst,
    u32* __restrict__ shist, u32* __restrict__ dhist, u32* __restrict__ pos) {
    int e = blockIdx.x * 256 + threadIdx.x;
    if (e < N_EDGES) {
        atomicAdd(&shist[src[e]], 1u);               // non-returning
        pos[e] = atomicAdd(&dhist[dst[e]], 1u);      // returning: rank within dst row
    }
}

// ---------------------------------------------------------------- norms from histograms
__global__ __launch_bounds__(256) void norm_kernel(
    const u32* __restrict__ dhist, const u32* __restrict__ shist,
    float* __restrict__ norm_src, float* __restrict__ norm_dst) {
    int n = blockIdx.x * 256 + threadIdx.x;
    if (n >= N_NODES) return;
    u32 id = dhist[n], od = shist[n];
    norm_dst[n] = rsqrtf((float)(id < 1u ? 1u : id));
    norm_src[n] = rsqrtf((float)(od < 1u ? 1u : od));
}

// ---------------------------------------------------------------- exclusive scan of dhist -> row_ptr (2-level)
#define SCAN_B 512
#define SCAN_NBLK ((N_NODES + SCAN_B - 1) / SCAN_B)   // 196

__global__ __launch_bounds__(SCAN_B) void scan1_kernel(
    const u32* __restrict__ indeg, u32* __restrict__ row_ptr, u32* __restrict__ bsum) {
    __shared__ u32 s[SCAN_B];
    int t = threadIdx.x;
    int gid = blockIdx.x * SCAN_B + t;
    u32 v = (gid < N_NODES) ? indeg[gid] : 0u;
    s[t] = v;
    __syncthreads();
    for (int off = 1; off < SCAN_B; off <<= 1) {
        u32 x = (t >= off) ? s[t - off] : 0u;
        __syncthreads();
        s[t] += x;
        __syncthreads();
    }
    if (gid < N_NODES) row_ptr[gid + 1] = s[t];
    if (t == SCAN_B - 1) bsum[blockIdx.x] = s[t];
}

__global__ __launch_bounds__(256) void scan2_kernel(u32* __restrict__ bsum, u32* __restrict__ boff) {
    __shared__ u32 s[256];
    int t = threadIdx.x;
    s[t] = (t < SCAN_NBLK) ? bsum[t] : 0u;
    __syncthreads();
    for (int off = 1; off < 256; off <<= 1) {
        u32 x = (t >= off) ? s[t - off] : 0u;
        __syncthreads();
        s[t] += x;
        __syncthreads();
    }
    if (t < SCAN_NBLK) boff[t] = (t == 0) ? 0u : s[t - 1];
}

__global__ __launch_bounds__(256) void scan3_kernel(u32* __restrict__ row_ptr, const u32* __restrict__ boff) {
    int gid = blockIdx.x * 256 + threadIdx.x;
    if (gid < N_NODES) {
        row_ptr[gid + 1] += boff[gid / SCAN_B];
        if (gid == 0) row_ptr[0] = 0u;
    }
}

// ---------------------------------------------------------------- CSR fill, atomic-free
__global__ __launch_bounds__(256) void fill_kernel(
    const int* __restrict__ src, const int* __restrict__ dst,
    const u32* __restrict__ row_ptr, const u32* __restrict__ pos,
    u32* __restrict__ col) {
    int e = blockIdx.x * 256 + threadIdx.x;
    if (e < N_EDGES) {
        int d = dst[e];
        col[row_ptr[d] + pos[e]] = (u32)src[e];
    }
}

// ---------------------------------------------------------------- GEMM: T[n,:] = bf16(norm_src[n] * (h[n,:] @ W))
template <int DIN, int DOUT>
__global__ __launch_bounds__(256) void gemm_kernel(
    const float* __restrict__ h, const float* __restrict__ W,
    const float* __restrict__ norm_src, u16* __restrict__ T) {
    constexpr int TM = 64;
    constexpr int KT = 32;
    constexpr int JBLKS = DOUT / 4;
    constexpr int NPT = (TM * DOUT) / (256 * 4);

    __shared__ float hs[KT][TM + 4];
    __shared__ float ws[KT][DOUT];

    const int t = threadIdx.x;
    const int m0 = blockIdx.x * TM;
    const int jblk = t % JBLKS;
    const int nblk = t / JBLKS;
    const int n0 = nblk * NPT;

    float acc[NPT][4];
    for (int i = 0; i < NPT; ++i)
        for (int j = 0; j < 4; ++j) acc[i][j] = 0.f;

    for (int k0 = 0; k0 < DIN; k0 += KT) {
        for (int it = 0; it < 2; ++it) {
            int f = t + it * 256;
            int row = f / (KT / 4);
            int c4  = f % (KT / 4);
            float4 v = make_float4(0.f, 0.f, 0.f, 0.f);
            int gr = m0 + row;
            if (gr < N_NODES)
                v = *reinterpret_cast<const float4*>(&h[gr * DIN + k0 + c4 * 4]);
            hs[c4 * 4 + 0][row] = v.x;
            hs[c4 * 4 + 1][row] = v.y;
            hs[c4 * 4 + 2][row] = v.z;
            hs[c4 * 4 + 3][row] = v.w;
        }
        constexpr int WQ = KT * DOUT / 4;
        constexpr int WITERS = (WQ + 255) / 256;
        for (int it = 0; it < WITERS; ++it) {
            int f = t + it * 256;
            if (f < WQ) {
                int row = f / JBLKS;
                int c4  = f % JBLKS;
                *reinterpret_cast<float4*>(&ws[row][c4 * 4]) =
                    *reinterpret_cast<const float4*>(&W[(k0 + row) * DOUT + c4 * 4]);
            }
        }
        __syncthreads();

#pragma unroll 4
        for (int k = 0; k < KT; ++k) {
            float4 wv = *reinterpret_cast<const float4*>(&ws[k][jblk * 4]);
            float a[NPT];
            if constexpr (NPT % 4 == 0) {
#pragma unroll
                for (int i = 0; i < NPT; i += 4)
                    *reinterpret_cast<float4*>(&a[i]) =
                        *reinterpret_cast<const float4*>(&hs[k][n0 + i]);
            } else if constexpr (NPT == 2) {
                *reinterpret_cast<float2*>(&a[0]) =
                    *reinterpret_cast<const float2*>(&hs[k][n0]);
            } else {
                a[0] = hs[k][n0];
            }
#pragma unroll
            for (int i = 0; i < NPT; ++i) {
                acc[i][0] = fmaf(a[i], wv.x, acc[i][0]);
                acc[i][1] = fmaf(a[i], wv.y, acc[i][1]);
                acc[i][2] = fmaf(a[i], wv.z, acc[i][2]);
                acc[i][3] = fmaf(a[i], wv.w, acc[i][3]);
            }
        }
        __syncthreads();
    }

#pragma unroll
    for (int i = 0; i < NPT; ++i) {
        int n = m0 + n0 + i;
        if (n < N_NODES) {
            float s = norm_src[n];
            ushort4 o;
            o.x = f2bf(acc[i][0] * s);
            o.y = f2bf(acc[i][1] * s);
            o.z = f2bf(acc[i][2] * s);
            o.w = f2bf(acc[i][3] * s);
            *reinterpret_cast<ushort4*>(&T[n * DOUT + jblk * 4]) = o;
        }
    }
}

// ---------------------------------------------------------------- pull + fused finalize (TPN = D/8, ushort8 gathers)
template <int D>
__global__ __launch_bounds__(256) void pull_kernel(
    const u16* __restrict__ T, const u32* __restrict__ row_ptr,
    const u32* __restrict__ col, const float* __restrict__ norm_dst,
    const float* __restrict__ b, const float* __restrict__ sb,
    float* __restrict__ h) {
    constexpr int TPN = D / 8;
    int tid = blockIdx.x * 256 + threadIdx.x;
    int n = tid / TPN;
    int c = (tid % TPN) * 8;
    if (n >= N_NODES) return;

    u32 beg = row_ptr[n], end = row_ptr[n + 1];
    float a[8];
#pragma unroll
    for (int j = 0; j < 8; ++j) a[j] = 0.f;

    u32 e = beg;
    for (; e + 1 < end; e += 2) {
        u32 s0 = col[e], s1 = col[e + 1];
        uint4 q0 = *reinterpret_cast<const uint4*>(&T[s0 * D + c]);
        uint4 q1 = *reinterpret_cast<const uint4*>(&T[s1 * D + c]);
        a[0] += bflo(q0.x) + bflo(q1.x);
        a[1] += bfhi(q0.x) + bfhi(q1.x);
        a[2] += bflo(q0.y) + bflo(q1.y);
        a[3] += bfhi(q0.y) + bfhi(q1.y);
        a[4] += bflo(q0.z) + bflo(q1.z);
        a[5] += bfhi(q0.z) + bfhi(q1.z);
        a[6] += bflo(q0.w) + bflo(q1.w);
        a[7] += bfhi(q0.w) + bfhi(q1.w);
    }
    if (e < end) {
        uint4 q0 = *reinterpret_cast<const uint4*>(&T[col[e] * D + c]);
        a[0] += bflo(q0.x); a[1] += bfhi(q0.x);
        a[2] += bflo(q0.y); a[3] += bfhi(q0.y);
        a[4] += bflo(q0.z); a[5] += bfhi(q0.z);
        a[6] += bflo(q0.w); a[7] += bfhi(q0.w);
    }

    float nd = norm_dst[n];
    float sv = sb[0];
    float4 b0 = *reinterpret_cast<const float4*>(&b[c]);
    float4 b1 = *reinterpret_cast<const float4*>(&b[c + 4]);
    float4 o0, o1;
    o0.x = fmaxf(a[0] * nd + b0.x + sv, 0.f);
    o0.y = fmaxf(a[1] * nd + b0.y + sv, 0.f);
    o0.z = fmaxf(a[2] * nd + b0.z + sv, 0.f);
    o0.w = fmaxf(a[3] * nd + b0.w + sv, 0.f);
    o1.x = fmaxf(a[4] * nd + b1.x + sv, 0.f);
    o1.y = fmaxf(a[5] * nd + b1.y + sv, 0.f);
    o1.z = fmaxf(a[6] * nd + b1.z + sv, 0.f);
    o1.w = fmaxf(a[7] * nd + b1.w + sv, 0.f);
    *reinterpret_cast<float4*>(&h[n * D + c])     = o0;
    *reinterpret_cast<float4*>(&h[n * D + c + 4]) = o1;
}

// ---------------------------------------------------------------- last layer: pull + finalize + softmax -> f32 out
// 2 threads per node, each owns 8 of 16 classes; cross-half reduce via shfl_xor(1).
__global__ __launch_bounds__(256) void pull16_sm_kernel(
    const u16* __restrict__ T, const u32* __restrict__ row_ptr,
    const u32* __restrict__ col, const float* __restrict__ norm_dst,
    const float* __restrict__ b, const float* __restrict__ sb,
    float* __restrict__ out) {
    int tid = blockIdx.x * 256 + threadIdx.x;
    int n = tid >> 1;
    int c = (tid & 1) * 8;
    if (n >= N_NODES) return;

    u32 beg = row_ptr[n], end = row_ptr[n + 1];
    float a[8];
#pragma unroll
    for (int j = 0; j < 8; ++j) a[j] = 0.f;

    u32 e = beg;
    for (; e + 1 < end; e += 2) {
        u32 s0 = col[e], s1 = col[e + 1];
        uint4 q0 = *reinterpret_cast<const uint4*>(&T[s0 * 16 + c]);
        uint4 q1 = *reinterpret_cast<const uint4*>(&T[s1 * 16 + c]);
        a[0] += bflo(q0.x) + bflo(q1.x);
        a[1] += bfhi(q0.x) + bfhi(q1.x);
        a[2] += bflo(q0.y) + bflo(q1.y);
        a[3] += bfhi(q0.y) + bfhi(q1.y);
        a[4] += bflo(q0.z) + bflo(q1.z);
        a[5] += bfhi(q0.z) + bfhi(q1.z);
        a[6] += bflo(q0.w) + bflo(q1.w);
        a[7] += bfhi(q0.w) + bfhi(q1.w);
    }
    if (e < end) {
        uint4 q0 = *reinterpret_cast<const uint4*>(&T[col[e] * 16 + c]);
        a[0] += bflo(q0.x); a[1] += bfhi(q0.x);
        a[2] += bflo(q0.y); a[3] += bfhi(q0.y);
        a[4] += bflo(q0.z); a[5] += bfhi(q0.z);
        a[6] += bflo(q0.w); a[7] += bfhi(q0.w);
    }

    float nd = norm_dst[n];
    float sv = sb[0];
    float4 b0 = *reinterpret_cast<const float4*>(&b[c]);
    float4 b1 = *reinterpret_cast<const float4*>(&b[c + 4]);
    float o[8];
    o[0] = fmaxf(a[0] * nd + b0.x + sv, 0.f);
    o[1] = fmaxf(a[1] * nd + b0.y + sv, 0.f);
    o[2] = fmaxf(a[2] * nd + b0.z + sv, 0.f);
    o[3] = fmaxf(a[3] * nd + b0.w + sv, 0.f);
    o[4] = fmaxf(a[4] * nd + b1.x + sv, 0.f);
    o[5] = fmaxf(a[5] * nd + b1.y + sv, 0.f);
    o[6] = fmaxf(a[6] * nd + b1.z + sv, 0.f);
    o[7] = fmaxf(a[7] * nd + b1.w + sv, 0.f);

    float m = o[0];
#pragma unroll
    for (int j = 1; j < 8; ++j) m = fmaxf(m, o[j]);
    m = fmaxf(m, __shfl_xor(m, 1));
    float s = 0.f;
#pragma unroll
    for (int j = 0; j < 8; ++j) { o[j] = __expf(o[j] - m); s += o[j]; }
    s += __shfl_xor(s, 1);
    float inv = 1.f / s;
    float4 w0 = make_float4(o[0] * inv, o[1] * inv, o[2] * inv, o[3] * inv);
    float4 w1 = make_float4(o[4] * inv, o[5] * inv, o[6] * inv, o[7] * inv);
    *reinterpret_cast<float4*>(&out[n * 16 + c])     = w0;
    *reinterpret_cast<float4*>(&out[n * 16 + c + 4]) = w1;
}

// ---------------------------------------------------------------- launch
extern "C" void kernel_launch(void* const* d_in, const int* in_sizes, int n_in,
                              void* d_out, int out_size, void* d_ws, size_t ws_size,
                              hipStream_t stream) {
    const float* x   = (const float*)d_in[0];
    const int*   src = (const int*)d_in[1];
    const int*   dst = (const int*)d_in[2];
    const float* W0 = (const float*)d_in[3];
    const float* b0 = (const float*)d_in[4];
    const float* sb0 = (const float*)d_in[5];
    const float* W1 = (const float*)d_in[6];
    const float* b1 = (const float*)d_in[7];
    const float* sb1 = (const float*)d_in[8];
    const float* W2 = (const float*)d_in[9];
    const float* b2 = (const float*)d_in[10];
    const float* sb2 = (const float*)d_in[11];
    const float* W3 = (const float*)d_in[12];
    const float* b3 = (const float*)d_in[13];
    const float* sb3 = (const float*)d_in[14];

    // workspace layout (peak ~84.4 MB):
    //   h    f32  N*128      @ 0
    //   T    bf16 N*128      @ 51.2M   — during CSR build this region holds:
    //        dhist u32 N     @ T+0       (in-degree; also scan1 input)
    //        shist u32 N     @ T+400K    (out-degree)
    //        pos   u32 E     @ T+800K    (per-edge rank within dst row)
    //   col  u32  E          @ 76.8M
    //   row_ptr u32 N+1      @ 83.2M
    //   norm_src f32 N       @ 83,600,016
    //   norm_dst f32 N       @ 84,000,016
    //   bsum/boff u32        @ 84,400,016
    char* ws = (char*)d_ws;
    float* h        = (float*)ws;
    u16*   T        = (u16*)(ws + 51200000);
    u32*   dhist    = (u32*)(ws + 51200000);
    u32*   shist    = (u32*)(ws + 51600000);
    u32*   pos      = (u32*)(ws + 52000000);
    u32*   col      = (u32*)(ws + 76800000);
    u32*   row_ptr  = (u32*)(ws + 83200000);
    float* norm_src = (float*)(ws + 83600016);
    float* norm_dst = (float*)(ws + 84000016);
    u32*   bsum     = (u32*)(ws + 84400016);
    u32*   boff     = (u32*)(ws + 84404016);

    const int EB = (N_EDGES + 255) / 256;
    const int NB = (N_NODES + 255) / 256;
    const int MT = (N_NODES + 63) / 64;

    // ---- CSR build + norms
    hipMemsetAsync(dhist, 0, 2 * N_NODES * 4, stream);   // dhist + shist contiguous
    degree_kernel<<<EB, 256, 0, stream>>>(src, dst, shist, dhist, pos);
    norm_kernel<<<NB, 256, 0, stream>>>(dhist, shist, norm_src, norm_dst);
    scan1_kernel<<<SCAN_NBLK, SCAN_B, 0, stream>>>(dhist, row_ptr, bsum);
    scan2_kernel<<<1, 256, 0, stream>>>(bsum, boff);
    scan3_kernel<<<NB, 256, 0, stream>>>(row_ptr, boff);
    fill_kernel<<<EB, 256, 0, stream>>>(src, dst, row_ptr, pos, col);

    // ---- layer 0: 256 -> 128
    gemm_kernel<256, 128><<<MT, 256, 0, stream>>>(x, W0, norm_src, T);
    pull_kernel<128><<<(N_NODES * 16 + 255) / 256, 256, 0, stream>>>(T, row_ptr, col, norm_dst, b0, sb0, h);

    // ---- layer 1: 128 -> 64
    gemm_kernel<128, 64><<<MT, 256, 0, stream>>>(h, W1, norm_src, T);
    pull_kernel<64><<<(N_NODES * 8 + 255) / 256, 256, 0, stream>>>(T, row_ptr, col, norm_dst, b1, sb1, h);

    // ---- layer 2: 64 -> 32
    gemm_kernel<64, 32><<<MT, 256, 0, stream>>>(h, W2, norm_src, T);
    pull_kernel<32><<<(N_NODES * 4 + 255) / 256, 256, 0, stream>>>(T, row_ptr, col, norm_dst, b2, sb2, h);

    // ---- layer 3: 32 -> 16 + fused softmax -> f32 out
    gemm_kernel<32, 16><<<MT, 256, 0, stream>>>(h, W3, norm_src, T);
    pull16_sm_kernel<<<(N_NODES * 2 + 255) / 256, 256, 0, stream>>>(T, row_ptr, col, norm_dst, b3, sb3, (float*)d_out);
}

// Round 11
// 572.758 us; speedup vs baseline: 9.5246x; 1.0778x over previous
//
#include <hip/hip_runtime.h>
#include <hip/hip_bf16.h>

#define N_NODES 100000
#define N_EDGES 1600000
#define NRANGE 16
#define NSLICE 32
#define RSZ (N_NODES / NRANGE)      // 6250 nodes per range
#define ESL (N_EDGES / NSLICE)      // 50000 edges per slice
#define EQ (ESL / 4)                // 12500 uint4 per slice

typedef unsigned short u16;
typedef unsigned int u32;

// bf16 -> f32 expansion (exact) and f32 -> bf16 (RNE)
static __device__ __forceinline__ u16 f2bf(float f) {
    union { float f; u32 u; } v; v.f = f;
    u32 u = v.u;
    u += 0x7FFFu + ((u >> 16) & 1u);
    return (u16)(u >> 16);
}
static __device__ __forceinline__ float bflo(u32 w) {
    union { u32 u; float f; } v; v.u = w << 16; return v.f;
}
static __device__ __forceinline__ float bfhi(u32 w) {
    union { u32 u; float f; } v; v.u = w & 0xFFFF0000u; return v.f;
}

// ---------------------------------------------------------------- partitioned histograms (no global atomics)
// block = (range r, slice s). LDS-count src/dst values in range; store counts coalesced.
__global__ __launch_bounds__(256) void hist_kernel(
    const int* __restrict__ src, const int* __restrict__ dst,
    u32* __restrict__ dslice, u32* __restrict__ sslice) {
    __shared__ u32 db[RSZ];
    __shared__ u32 sb[RSZ];
    const int t = threadIdx.x;
    const int r = blockIdx.x & (NRANGE - 1);
    const int s = blockIdx.x >> 4;
    const u32 r0 = (u32)r * RSZ;
    for (int i = t; i < RSZ; i += 256) { db[i] = 0u; sb[i] = 0u; }
    __syncthreads();
    const int e0 = s * ESL;
    for (int k = t; k < EQ; k += 256) {
        int idx = e0 + k * 4;
        uint4 d4 = *reinterpret_cast<const uint4*>(&dst[idx]);
        uint4 s4 = *reinterpret_cast<const uint4*>(&src[idx]);
        u32 li;
        li = d4.x - r0; if (li < RSZ) atomicAdd(&db[li], 1u);
        li = d4.y - r0; if (li < RSZ) atomicAdd(&db[li], 1u);
        li = d4.z - r0; if (li < RSZ) atomicAdd(&db[li], 1u);
        li = d4.w - r0; if (li < RSZ) atomicAdd(&db[li], 1u);
        li = s4.x - r0; if (li < RSZ) atomicAdd(&sb[li], 1u);
        li = s4.y - r0; if (li < RSZ) atomicAdd(&sb[li], 1u);
        li = s4.z - r0; if (li < RSZ) atomicAdd(&sb[li], 1u);
        li = s4.w - r0; if (li < RSZ) atomicAdd(&sb[li], 1u);
    }
    __syncthreads();
    u32* dbase = dslice + (size_t)(r * NSLICE + s) * RSZ;
    u32* sbase = sslice + (size_t)(r * NSLICE + s) * RSZ;
    for (int i = t; i < RSZ; i += 256) { dbase[i] = db[i]; sbase[i] = sb[i]; }
}

// ---------------------------------------------------------------- per-node: slice-offsets (in place), indeg, norms
__global__ __launch_bounds__(256) void prep_kernel(
    u32* __restrict__ dslice, const u32* __restrict__ sslice,
    u32* __restrict__ indeg, float* __restrict__ norm_src, float* __restrict__ norm_dst) {
    int n = blockIdx.x * 256 + threadIdx.x;
    if (n >= N_NODES) return;
    int r = n / RSZ;
    int i = n - r * RSZ;
    size_t base = (size_t)(r * NSLICE) * RSZ + i;
    u32 accd = 0u, accs = 0u;
#pragma unroll
    for (int s = 0; s < NSLICE; ++s) {
        u32 c = dslice[base + (size_t)s * RSZ];
        dslice[base + (size_t)s * RSZ] = accd;   // exclusive slice base
        accd += c;
        accs += sslice[base + (size_t)s * RSZ];
    }
    indeg[n] = accd;
    norm_dst[n] = rsqrtf((float)(accd < 1u ? 1u : accd));
    norm_src[n] = rsqrtf((float)(accs < 1u ? 1u : accs));
}

// ---------------------------------------------------------------- exclusive scan of indeg -> row_ptr (2-level)
#define SCAN_B 512
#define SCAN_NBLK ((N_NODES + SCAN_B - 1) / SCAN_B)   // 196

__global__ __launch_bounds__(SCAN_B) void scan1_kernel(
    const u32* __restrict__ indeg, u32* __restrict__ row_ptr, u32* __restrict__ bsum) {
    __shared__ u32 s[SCAN_B];
    int t = threadIdx.x;
    int gid = blockIdx.x * SCAN_B + t;
    u32 v = (gid < N_NODES) ? indeg[gid] : 0u;
    s[t] = v;
    __syncthreads();
    for (int off = 1; off < SCAN_B; off <<= 1) {
        u32 x = (t >= off) ? s[t - off] : 0u;
        __syncthreads();
        s[t] += x;
        __syncthreads();
    }
    if (gid < N_NODES) row_ptr[gid + 1] = s[t];
    if (t == SCAN_B - 1) bsum[blockIdx.x] = s[t];
}

__global__ __launch_bounds__(256) void scan2_kernel(u32* __restrict__ bsum, u32* __restrict__ boff) {
    __shared__ u32 s[256];
    int t = threadIdx.x;
    s[t] = (t < SCAN_NBLK) ? bsum[t] : 0u;
    __syncthreads();
    for (int off = 1; off < 256; off <<= 1) {
        u32 x = (t >= off) ? s[t - off] : 0u;
        __syncthreads();
        s[t] += x;
        __syncthreads();
    }
    if (t < SCAN_NBLK) boff[t] = (t == 0) ? 0u : s[t - 1];
}

__global__ __launch_bounds__(256) void scan3_kernel(u32* __restrict__ row_ptr, const u32* __restrict__ boff) {
    int gid = blockIdx.x * 256 + threadIdx.x;
    if (gid < N_NODES) {
        row_ptr[gid + 1] += boff[gid / SCAN_B];
        if (gid == 0) row_ptr[0] = 0u;
    }
}

// ---------------------------------------------------------------- CSR fill: LDS ranks + slice bases (no global atomics)
__global__ __launch_bounds__(256) void fill2_kernel(
    const int* __restrict__ src, const int* __restrict__ dst,
    const u32* __restrict__ row_ptr, const u32* __restrict__ dslice,
    u32* __restrict__ col) {
    __shared__ u32 cur[RSZ];
    const int t = threadIdx.x;
    const int r = blockIdx.x & (NRANGE - 1);
    const int s = blockIdx.x >> 4;
    const u32 r0 = (u32)r * RSZ;
    const u32* dbase = dslice + (size_t)(r * NSLICE + s) * RSZ;
    for (int i = t; i < RSZ; i += 256) cur[i] = 0u;
    __syncthreads();
    const int e0 = s * ESL;
    for (int k = t; k < EQ; k += 256) {
        int idx = e0 + k * 4;
        uint4 d4 = *reinterpret_cast<const uint4*>(&dst[idx]);
        uint4 s4 = *reinterpret_cast<const uint4*>(&src[idx]);
        u32 li, rk;
        li = d4.x - r0; if (li < RSZ) { rk = atomicAdd(&cur[li], 1u); col[row_ptr[d4.x] + dbase[li] + rk] = s4.x; }
        li = d4.y - r0; if (li < RSZ) { rk = atomicAdd(&cur[li], 1u); col[row_ptr[d4.y] + dbase[li] + rk] = s4.y; }
        li = d4.z - r0; if (li < RSZ) { rk = atomicAdd(&cur[li], 1u); col[row_ptr[d4.z] + dbase[li] + rk] = s4.z; }
        li = d4.w - r0; if (li < RSZ) { rk = atomicAdd(&cur[li], 1u); col[row_ptr[d4.w] + dbase[li] + rk] = s4.w; }
    }
}

// ---------------------------------------------------------------- GEMM: T[n,:] = bf16(norm_src[n] * (h[n,:] @ W))
template <int DIN, int DOUT>
__global__ __launch_bounds__(256) void gemm_kernel(
    const float* __restrict__ h, const float* __restrict__ W,
    const float* __restrict__ norm_src, u16* __restrict__ T) {
    constexpr int TM = 64;
    constexpr int KT = 32;
    constexpr int JBLKS = DOUT / 4;
    constexpr int NPT = (TM * DOUT) / (256 * 4);

    __shared__ float hs[KT][TM + 4];
    __shared__ float ws[KT][DOUT];

    const int t = threadIdx.x;
    const int m0 = blockIdx.x * TM;
    const int jblk = t % JBLKS;
    const int nblk = t / JBLKS;
    const int n0 = nblk * NPT;

    float acc[NPT][4];
    for (int i = 0; i < NPT; ++i)
        for (int j = 0; j < 4; ++j) acc[i][j] = 0.f;

    for (int k0 = 0; k0 < DIN; k0 += KT) {
        for (int it = 0; it < 2; ++it) {
            int f = t + it * 256;
            int row = f / (KT / 4);
            int c4  = f % (KT / 4);
            float4 v = make_float4(0.f, 0.f, 0.f, 0.f);
            int gr = m0 + row;
            if (gr < N_NODES)
                v = *reinterpret_cast<const float4*>(&h[gr * DIN + k0 + c4 * 4]);
            hs[c4 * 4 + 0][row] = v.x;
            hs[c4 * 4 + 1][row] = v.y;
            hs[c4 * 4 + 2][row] = v.z;
            hs[c4 * 4 + 3][row] = v.w;
        }
        constexpr int WQ = KT * DOUT / 4;
        constexpr int WITERS = (WQ + 255) / 256;
        for (int it = 0; it < WITERS; ++it) {
            int f = t + it * 256;
            if (f < WQ) {
                int row = f / JBLKS;
                int c4  = f % JBLKS;
                *reinterpret_cast<float4*>(&ws[row][c4 * 4]) =
                    *reinterpret_cast<const float4*>(&W[(k0 + row) * DOUT + c4 * 4]);
            }
        }
        __syncthreads();

#pragma unroll 4
        for (int k = 0; k < KT; ++k) {
            float4 wv = *reinterpret_cast<const float4*>(&ws[k][jblk * 4]);
            float a[NPT];
            if constexpr (NPT % 4 == 0) {
#pragma unroll
                for (int i = 0; i < NPT; i += 4)
                    *reinterpret_cast<float4*>(&a[i]) =
                        *reinterpret_cast<const float4*>(&hs[k][n0 + i]);
            } else if constexpr (NPT == 2) {
                *reinterpret_cast<float2*>(&a[0]) =
                    *reinterpret_cast<const float2*>(&hs[k][n0]);
            } else {
                a[0] = hs[k][n0];
            }
#pragma unroll
            for (int i = 0; i < NPT; ++i) {
                acc[i][0] = fmaf(a[i], wv.x, acc[i][0]);
                acc[i][1] = fmaf(a[i], wv.y, acc[i][1]);
                acc[i][2] = fmaf(a[i], wv.z, acc[i][2]);
                acc[i][3] = fmaf(a[i], wv.w, acc[i][3]);
            }
        }
        __syncthreads();
    }

#pragma unroll
    for (int i = 0; i < NPT; ++i) {
        int n = m0 + n0 + i;
        if (n < N_NODES) {
            float s = norm_src[n];
            ushort4 o;
            o.x = f2bf(acc[i][0] * s);
            o.y = f2bf(acc[i][1] * s);
            o.z = f2bf(acc[i][2] * s);
            o.w = f2bf(acc[i][3] * s);
            *reinterpret_cast<ushort4*>(&T[n * DOUT + jblk * 4]) = o;
        }
    }
}

// ---------------------------------------------------------------- pull + fused finalize (TPN = D/8, ushort8 gathers)
template <int D>
__global__ __launch_bounds__(256) void pull_kernel(
    const u16* __restrict__ T, const u32* __restrict__ row_ptr,
    const u32* __restrict__ col, const float* __restrict__ norm_dst,
    const float* __restrict__ b, const float* __restrict__ sb,
    float* __restrict__ h) {
    constexpr int TPN = D / 8;
    int tid = blockIdx.x * 256 + threadIdx.x;
    int n = tid / TPN;
    int c = (tid % TPN) * 8;
    if (n >= N_NODES) return;

    u32 beg = row_ptr[n], end = row_ptr[n + 1];
    float a[8];
#pragma unroll
    for (int j = 0; j < 8; ++j) a[j] = 0.f;

    u32 e = beg;
    for (; e + 1 < end; e += 2) {
        u32 s0 = col[e], s1 = col[e + 1];
        uint4 q0 = *reinterpret_cast<const uint4*>(&T[s0 * D + c]);
        uint4 q1 = *reinterpret_cast<const uint4*>(&T[s1 * D + c]);
        a[0] += bflo(q0.x) + bflo(q1.x);
        a[1] += bfhi(q0.x) + bfhi(q1.x);
        a[2] += bflo(q0.y) + bflo(q1.y);
        a[3] += bfhi(q0.y) + bfhi(q1.y);
        a[4] += bflo(q0.z) + bflo(q1.z);
        a[5] += bfhi(q0.z) + bfhi(q1.z);
        a[6] += bflo(q0.w) + bflo(q1.w);
        a[7] += bfhi(q0.w) + bfhi(q1.w);
    }
    if (e < end) {
        uint4 q0 = *reinterpret_cast<const uint4*>(&T[col[e] * D + c]);
        a[0] += bflo(q0.x); a[1] += bfhi(q0.x);
        a[2] += bflo(q0.y); a[3] += bfhi(q0.y);
        a[4] += bflo(q0.z); a[5] += bfhi(q0.z);
        a[6] += bflo(q0.w); a[7] += bfhi(q0.w);
    }

    float nd = norm_dst[n];
    float sv = sb[0];
    float4 b0 = *reinterpret_cast<const float4*>(&b[c]);
    float4 b1 = *reinterpret_cast<const float4*>(&b[c + 4]);
    float4 o0, o1;
    o0.x = fmaxf(a[0] * nd + b0.x + sv, 0.f);
    o0.y = fmaxf(a[1] * nd + b0.y + sv, 0.f);
    o0.z = fmaxf(a[2] * nd + b0.z + sv, 0.f);
    o0.w = fmaxf(a[3] * nd + b0.w + sv, 0.f);
    o1.x = fmaxf(a[4] * nd + b1.x + sv, 0.f);
    o1.y = fmaxf(a[5] * nd + b1.y + sv, 0.f);
    o1.z = fmaxf(a[6] * nd + b1.z + sv, 0.f);
    o1.w = fmaxf(a[7] * nd + b1.w + sv, 0.f);
    *reinterpret_cast<float4*>(&h[n * D + c])     = o0;
    *reinterpret_cast<float4*>(&h[n * D + c + 4]) = o1;
}

// ---------------------------------------------------------------- last layer: pull + finalize + softmax -> f32 out
__global__ __launch_bounds__(256) void pull16_sm_kernel(
    const u16* __restrict__ T, const u32* __restrict__ row_ptr,
    const u32* __restrict__ col, const float* __restrict__ norm_dst,
    const float* __restrict__ b, const float* __restrict__ sb,
    float* __restrict__ out) {
    int tid = blockIdx.x * 256 + threadIdx.x;
    int n = tid >> 1;
    int c = (tid & 1) * 8;
    if (n >= N_NODES) return;

    u32 beg = row_ptr[n], end = row_ptr[n + 1];
    float a[8];
#pragma unroll
    for (int j = 0; j < 8; ++j) a[j] = 0.f;

    u32 e = beg;
    for (; e + 1 < end; e += 2) {
        u32 s0 = col[e], s1 = col[e + 1];
        uint4 q0 = *reinterpret_cast<const uint4*>(&T[s0 * 16 + c]);
        uint4 q1 = *reinterpret_cast<const uint4*>(&T[s1 * 16 + c]);
        a[0] += bflo(q0.x) + bflo(q1.x);
        a[1] += bfhi(q0.x) + bfhi(q1.x);
        a[2] += bflo(q0.y) + bflo(q1.y);
        a[3] += bfhi(q0.y) + bfhi(q1.y);
        a[4] += bflo(q0.z) + bflo(q1.z);
        a[5] += bfhi(q0.z) + bfhi(q1.z);
        a[6] += bflo(q0.w) + bflo(q1.w);
        a[7] += bfhi(q0.w) + bfhi(q1.w);
    }
    if (e < end) {
        uint4 q0 = *reinterpret_cast<const uint4*>(&T[col[e] * 16 + c]);
        a[0] += bflo(q0.x); a[1] += bfhi(q0.x);
        a[2] += bflo(q0.y); a[3] += bfhi(q0.y);
        a[4] += bflo(q0.z); a[5] += bfhi(q0.z);
        a[6] += bflo(q0.w); a[7] += bfhi(q0.w);
    }

    float nd = norm_dst[n];
    float sv = sb[0];
    float4 b0 = *reinterpret_cast<const float4*>(&b[c]);
    float4 b1 = *reinterpret_cast<const float4*>(&b[c + 4]);
    float o[8];
    o[0] = fmaxf(a[0] * nd + b0.x + sv, 0.f);
    o[1] = fmaxf(a[1] * nd + b0.y + sv, 0.f);
    o[2] = fmaxf(a[2] * nd + b0.z + sv, 0.f);
    o[3] = fmaxf(a[3] * nd + b0.w + sv, 0.f);
    o[4] = fmaxf(a[4] * nd + b1.x + sv, 0.f);
    o[5] = fmaxf(a[5] * nd + b1.y + sv, 0.f);
    o[6] = fmaxf(a[6] * nd + b1.z + sv, 0.f);
    o[7] = fmaxf(a[7] * nd + b1.w + sv, 0.f);

    float m = o[0];
#pragma unroll
    for (int j = 1; j < 8; ++j) m = fmaxf(m, o[j]);
    m = fmaxf(m, __shfl_xor(m, 1));
    float s = 0.f;
#pragma unroll
    for (int j = 0; j < 8; ++j) { o[j] = __expf(o[j] - m); s += o[j]; }
    s += __shfl_xor(s, 1);
    float inv = 1.f / s;
    float4 w0 = make_float4(o[0] * inv, o[1] * inv, o[2] * inv, o[3] * inv);
    float4 w1 = make_float4(o[4] * inv, o[5] * inv, o[6] * inv, o[7] * inv);
    *reinterpret_cast<float4*>(&out[n * 16 + c])     = w0;
    *reinterpret_cast<float4*>(&out[n * 16 + c + 4]) = w1;
}

// ---------------------------------------------------------------- launch
extern "C" void kernel_launch(void* const* d_in, const int* in_sizes, int n_in,
                              void* d_out, int out_size, void* d_ws, size_t ws_size,
                              hipStream_t stream) {
    const float* x   = (const float*)d_in[0];
    const int*   src = (const int*)d_in[1];
    const int*   dst = (const int*)d_in[2];
    const float* W0 = (const float*)d_in[3];
    const float* b0 = (const float*)d_in[4];
    const float* sb0 = (const float*)d_in[5];
    const float* W1 = (const float*)d_in[6];
    const float* b1 = (const float*)d_in[7];
    const float* sb1 = (const float*)d_in[8];
    const float* W2 = (const float*)d_in[9];
    const float* b2 = (const float*)d_in[10];
    const float* sb2 = (const float*)d_in[11];
    const float* W3 = (const float*)d_in[12];
    const float* b3 = (const float*)d_in[13];
    const float* sb3 = (const float*)d_in[14];

    // workspace layout (peak ~84.4 MB):
    //   h      f32  N*128               @ 0
    //   T      bf16 N*128               @ 51.2M — during CSR build holds:
    //          dslice u32 16*32*6250    @ T+0      (12.8 MB: per-(range,slice) dst counts -> bases)
    //          sslice u32 16*32*6250    @ T+12.8M  (12.8 MB: per-(range,slice) src counts)
    //   col    u32  E                   @ 76.8M
    //   row_ptr u32 N+1                 @ 83.2M
    //   norm_src f32 N                  @ 83,600,016
    //   norm_dst f32 N                  @ 84,000,016
    //   bsum/boff u32                   @ 84,400,016
    //   indeg  u32 N                    @ 84,408,016
    char* ws = (char*)d_ws;
    float* h        = (float*)ws;
    u16*   T        = (u16*)(ws + 51200000);
    u32*   dslice   = (u32*)(ws + 51200000);
    u32*   sslice   = (u32*)(ws + 64000000);
    u32*   col      = (u32*)(ws + 76800000);
    u32*   row_ptr  = (u32*)(ws + 83200000);
    float* norm_src = (float*)(ws + 83600016);
    float* norm_dst = (float*)(ws + 84000016);
    u32*   bsum     = (u32*)(ws + 84400016);
    u32*   boff     = (u32*)(ws + 84404016);
    u32*   indeg    = (u32*)(ws + 84408016);

    const int NB = (N_NODES + 255) / 256;
    const int MT = (N_NODES + 63) / 64;

    // ---- CSR build + norms (no global atomics, no memsets)
    hist_kernel<<<NRANGE * NSLICE, 256, 0, stream>>>(src, dst, dslice, sslice);
    prep_kernel<<<NB, 256, 0, stream>>>(dslice, sslice, indeg, norm_src, norm_dst);
    scan1_kernel<<<SCAN_NBLK, SCAN_B, 0, stream>>>(indeg, row_ptr, bsum);
    scan2_kernel<<<1, 256, 0, stream>>>(bsum, boff);
    scan3_kernel<<<NB, 256, 0, stream>>>(row_ptr, boff);
    fill2_kernel<<<NRANGE * NSLICE, 256, 0, stream>>>(src, dst, row_ptr, dslice, col);

    // ---- layer 0: 256 -> 128
    gemm_kernel<256, 128><<<MT, 256, 0, stream>>>(x, W0, norm_src, T);
    pull_kernel<128><<<(N_NODES * 16 + 255) / 256, 256, 0, stream>>>(T, row_ptr, col, norm_dst, b0, sb0, h);

    // ---- layer 1: 128 -> 64
    gemm_kernel<128, 64><<<MT, 256, 0, stream>>>(h, W1, norm_src, T);
    pull_kernel<64><<<(N_NODES * 8 + 255) / 256, 256, 0, stream>>>(T, row_ptr, col, norm_dst, b1, sb1, h);

    // ---- layer 2: 64 -> 32
    gemm_kernel<64, 32><<<MT, 256, 0, stream>>>(h, W2, norm_src, T);
    pull_kernel<32><<<(N_NODES * 4 + 255) / 256, 256, 0, stream>>>(T, row_ptr, col, norm_dst, b2, sb2, h);

    // ---- layer 3: 32 -> 16 + fused softmax -> f32 out
    gemm_kernel<32, 16><<<MT, 256, 0, stream>>>(h, W3, norm_src, T);
    pull16_sm_kernel<<<(N_NODES * 2 + 255) / 256, 256, 0, stream>>>(T, row_ptr, col, norm_dst, b3, sb3, (float*)d_out);
}

// Round 12
// 528.759 us; speedup vs baseline: 10.3171x; 1.0832x over previous
//
#include <hip/hip_runtime.h>
#include <hip/hip_bf16.h>

#define N_NODES 100000
#define N_EDGES 1600000
#define NRANGE 16
#define NSLICE 32
#define RSZ (N_NODES / NRANGE)      // 6250 nodes per range
#define ESL (N_EDGES / NSLICE)      // 50000 edges per slice
#define EQ (ESL / 4)                // 12500 uint4 per slice

typedef unsigned short u16;
typedef unsigned int u32;

typedef float f32x4 __attribute__((ext_vector_type(4)));
typedef short bf16x8 __attribute__((ext_vector_type(8)));

// bf16 helpers
static __device__ __forceinline__ u16 f2bf(float f) {
    union { float f; u32 u; } v; v.f = f;
    u32 u = v.u;
    u += 0x7FFFu + ((u >> 16) & 1u);
    return (u16)(u >> 16);
}
static __device__ __forceinline__ float bflo(u32 w) {
    union { u32 u; float f; } v; v.u = w << 16; return v.f;
}
static __device__ __forceinline__ float bfhi(u32 w) {
    union { u32 u; float f; } v; v.u = w & 0xFFFF0000u; return v.f;
}
// pack 2 f32 -> 2 bf16 (RNE) in one dword: lo -> [15:0], hi -> [31:16]
static __device__ __forceinline__ u32 cvtpk(float lo, float hi) {
    u32 r;
    asm("v_cvt_pk_bf16_f32 %0, %1, %2" : "=v"(r) : "v"(lo), "v"(hi));
    return r;
}

// ---------------------------------------------------------------- partitioned histograms (no global atomics)
__global__ __launch_bounds__(256) void hist_kernel(
    const int* __restrict__ src, const int* __restrict__ dst,
    u32* __restrict__ dslice, u32* __restrict__ sslice) {
    __shared__ u32 db[RSZ];
    __shared__ u32 sb[RSZ];
    const int t = threadIdx.x;
    const int r = blockIdx.x & (NRANGE - 1);
    const int s = blockIdx.x >> 4;
    const u32 r0 = (u32)r * RSZ;
    for (int i = t; i < RSZ; i += 256) { db[i] = 0u; sb[i] = 0u; }
    __syncthreads();
    const int e0 = s * ESL;
    for (int k = t; k < EQ; k += 256) {
        int idx = e0 + k * 4;
        uint4 d4 = *reinterpret_cast<const uint4*>(&dst[idx]);
        uint4 s4 = *reinterpret_cast<const uint4*>(&src[idx]);
        u32 li;
        li = d4.x - r0; if (li < RSZ) atomicAdd(&db[li], 1u);
        li = d4.y - r0; if (li < RSZ) atomicAdd(&db[li], 1u);
        li = d4.z - r0; if (li < RSZ) atomicAdd(&db[li], 1u);
        li = d4.w - r0; if (li < RSZ) atomicAdd(&db[li], 1u);
        li = s4.x - r0; if (li < RSZ) atomicAdd(&sb[li], 1u);
        li = s4.y - r0; if (li < RSZ) atomicAdd(&sb[li], 1u);
        li = s4.z - r0; if (li < RSZ) atomicAdd(&sb[li], 1u);
        li = s4.w - r0; if (li < RSZ) atomicAdd(&sb[li], 1u);
    }
    __syncthreads();
    u32* dbase = dslice + (size_t)(r * NSLICE + s) * RSZ;
    u32* sbase = sslice + (size_t)(r * NSLICE + s) * RSZ;
    for (int i = t; i < RSZ; i += 256) { dbase[i] = db[i]; sbase[i] = sb[i]; }
}

// ---------------------------------------------------------------- per-node: slice offsets, indeg, norms
__global__ __launch_bounds__(256) void prep_kernel(
    u32* __restrict__ dslice, const u32* __restrict__ sslice,
    u32* __restrict__ indeg, float* __restrict__ norm_src, float* __restrict__ norm_dst) {
    int n = blockIdx.x * 256 + threadIdx.x;
    if (n >= N_NODES) return;
    int r = n / RSZ;
    int i = n - r * RSZ;
    size_t base = (size_t)(r * NSLICE) * RSZ + i;
    u32 accd = 0u, accs = 0u;
#pragma unroll
    for (int s = 0; s < NSLICE; ++s) {
        u32 c = dslice[base + (size_t)s * RSZ];
        dslice[base + (size_t)s * RSZ] = accd;
        accd += c;
        accs += sslice[base + (size_t)s * RSZ];
    }
    indeg[n] = accd;
    norm_dst[n] = rsqrtf((float)(accd < 1u ? 1u : accd));
    norm_src[n] = rsqrtf((float)(accs < 1u ? 1u : accs));
}

// ---------------------------------------------------------------- exclusive scan -> row_ptr (2-level)
#define SCAN_B 512
#define SCAN_NBLK ((N_NODES + SCAN_B - 1) / SCAN_B)   // 196

__global__ __launch_bounds__(SCAN_B) void scan1_kernel(
    const u32* __restrict__ indeg, u32* __restrict__ row_ptr, u32* __restrict__ bsum) {
    __shared__ u32 s[SCAN_B];
    int t = threadIdx.x;
    int gid = blockIdx.x * SCAN_B + t;
    u32 v = (gid < N_NODES) ? indeg[gid] : 0u;
    s[t] = v;
    __syncthreads();
    for (int off = 1; off < SCAN_B; off <<= 1) {
        u32 x = (t >= off) ? s[t - off] : 0u;
        __syncthreads();
        s[t] += x;
        __syncthreads();
    }
    if (gid < N_NODES) row_ptr[gid + 1] = s[t];
    if (t == SCAN_B - 1) bsum[blockIdx.x] = s[t];
}

__global__ __launch_bounds__(256) void scan2_kernel(u32* __restrict__ bsum, u32* __restrict__ boff) {
    __shared__ u32 s[256];
    int t = threadIdx.x;
    s[t] = (t < SCAN_NBLK) ? bsum[t] : 0u;
    __syncthreads();
    for (int off = 1; off < 256; off <<= 1) {
        u32 x = (t >= off) ? s[t - off] : 0u;
        __syncthreads();
        s[t] += x;
        __syncthreads();
    }
    if (t < SCAN_NBLK) boff[t] = (t == 0) ? 0u : s[t - 1];
}

__global__ __launch_bounds__(256) void scan3_kernel(u32* __restrict__ row_ptr, const u32* __restrict__ boff) {
    int gid = blockIdx.x * 256 + threadIdx.x;
    if (gid < N_NODES) {
        row_ptr[gid + 1] += boff[gid / SCAN_B];
        if (gid == 0) row_ptr[0] = 0u;
    }
}

// ---------------------------------------------------------------- CSR fill: LDS ranks + slice bases
__global__ __launch_bounds__(256) void fill2_kernel(
    const int* __restrict__ src, const int* __restrict__ dst,
    const u32* __restrict__ row_ptr, const u32* __restrict__ dslice,
    u32* __restrict__ col) {
    __shared__ u32 cur[RSZ];
    const int t = threadIdx.x;
    const int r = blockIdx.x & (NRANGE - 1);
    const int s = blockIdx.x >> 4;
    const u32 r0 = (u32)r * RSZ;
    const u32* dbase = dslice + (size_t)(r * NSLICE + s) * RSZ;
    for (int i = t; i < RSZ; i += 256) cur[i] = 0u;
    __syncthreads();
    const int e0 = s * ESL;
    for (int k = t; k < EQ; k += 256) {
        int idx = e0 + k * 4;
        uint4 d4 = *reinterpret_cast<const uint4*>(&dst[idx]);
        uint4 s4 = *reinterpret_cast<const uint4*>(&src[idx]);
        u32 li, rk;
        li = d4.x - r0; if (li < RSZ) { rk = atomicAdd(&cur[li], 1u); col[row_ptr[d4.x] + dbase[li] + rk] = s4.x; }
        li = d4.y - r0; if (li < RSZ) { rk = atomicAdd(&cur[li], 1u); col[row_ptr[d4.y] + dbase[li] + rk] = s4.y; }
        li = d4.z - r0; if (li < RSZ) { rk = atomicAdd(&cur[li], 1u); col[row_ptr[d4.z] + dbase[li] + rk] = s4.z; }
        li = d4.w - r0; if (li < RSZ) { rk = atomicAdd(&cur[li], 1u); col[row_ptr[d4.w] + dbase[li] + rk] = s4.w; }
    }
}

// ---------------------------------------------------------------- W transpose+bf16 prep (all 4 layers, one kernel)
// wt layout: Wt0[128][256] @0, Wt1[64][128] @32768, Wt2[32][64] @40960, Wt3[16][32] @43008 (elems)
__global__ __launch_bounds__(256) void wtprep_kernel(
    const float* __restrict__ W0, const float* __restrict__ W1,
    const float* __restrict__ W2, const float* __restrict__ W3,
    u16* __restrict__ wt) {
    int i = blockIdx.x * 256 + threadIdx.x;
    if (i >= 43520) return;
    const float* W; int DIN, DOUT, local;
    if (i < 32768)      { W = W0; DIN = 256; DOUT = 128; local = i; }
    else if (i < 40960) { W = W1; DIN = 128; DOUT = 64;  local = i - 32768; }
    else if (i < 43008) { W = W2; DIN = 64;  DOUT = 32;  local = i - 40960; }
    else                { W = W3; DIN = 32;  DOUT = 16;  local = i - 43008; }
    int j = local / DIN;
    int k = local - j * DIN;
    wt[i] = f2bf(W[k * DOUT + j]);
}

// ---------------------------------------------------------------- MFMA GEMM: T[n,:] = bf16(norm_src[n]*(h[n,:]@W))
// 256 thr = 4 waves; wave handles 2 row-tiles of 16 (block = 128 rows); no LDS.
// A frag: elem i = A[l&15][(l>>4)*8+i]; B frag: elem i = B[(l>>4)*8+i][l&15] = Wt[col][k];
// D frag: reg r = D[(l>>4)*4+r][l&15]  (m89-verified mapping)
template <int DIN, int DOUT>
__global__ __launch_bounds__(256) void mgemm_kernel(
    const float* __restrict__ h, const u16* __restrict__ Wt,
    const float* __restrict__ norm_src, u16* __restrict__ T) {
    constexpr int NT = DOUT / 16;
    constexpr int KS = DIN / 32;
    const int t = threadIdx.x;
    const int w = t >> 6;
    const int l = t & 63;
    const int lg = l >> 4;
    const int lr = l & 15;
    const int m0 = blockIdx.x * 128 + w * 32;

    const int ra0 = min(m0 + lr, N_NODES - 1);
    const int ra1 = min(m0 + 16 + lr, N_NODES - 1);

    f32x4 acc[2][NT];
#pragma unroll
    for (int m = 0; m < 2; ++m)
#pragma unroll
        for (int nt = 0; nt < NT; ++nt) acc[m][nt] = (f32x4){0.f, 0.f, 0.f, 0.f};

#pragma unroll
    for (int ks = 0; ks < KS; ++ks) {
        const int k0 = ks * 32 + lg * 8;
        // A frags: 8 f32 -> 8 bf16 via cvt_pk
        float4 a0 = *reinterpret_cast<const float4*>(&h[(size_t)ra0 * DIN + k0]);
        float4 a1 = *reinterpret_cast<const float4*>(&h[(size_t)ra0 * DIN + k0 + 4]);
        float4 b0 = *reinterpret_cast<const float4*>(&h[(size_t)ra1 * DIN + k0]);
        float4 b1 = *reinterpret_cast<const float4*>(&h[(size_t)ra1 * DIN + k0 + 4]);
        union { u32 u[4]; bf16x8 v; } af0, af1;
        af0.u[0] = cvtpk(a0.x, a0.y); af0.u[1] = cvtpk(a0.z, a0.w);
        af0.u[2] = cvtpk(a1.x, a1.y); af0.u[3] = cvtpk(a1.z, a1.w);
        af1.u[0] = cvtpk(b0.x, b0.y); af1.u[1] = cvtpk(b0.z, b0.w);
        af1.u[2] = cvtpk(b1.x, b1.y); af1.u[3] = cvtpk(b1.z, b1.w);
#pragma unroll
        for (int nt = 0; nt < NT; ++nt) {
            union { uint4 q; bf16x8 v; } bf;
            bf.q = *reinterpret_cast<const uint4*>(&Wt[(size_t)(nt * 16 + lr) * DIN + k0]);
            acc[0][nt] = __builtin_amdgcn_mfma_f32_16x16x32_bf16(af0.v, bf.v, acc[0][nt], 0, 0, 0);
            acc[1][nt] = __builtin_amdgcn_mfma_f32_16x16x32_bf16(af1.v, bf.v, acc[1][nt], 0, 0, 0);
        }
    }

    // epilogue: rows (l>>4)*4 + r within each 16-row tile, col = lr in each N-tile
#pragma unroll
    for (int m = 0; m < 2; ++m) {
        const int rbase = m0 + m * 16 + lg * 4;
#pragma unroll
        for (int r = 0; r < 4; ++r) {
            int row = rbase + r;
            if (row < N_NODES) {
                float ns = norm_src[row];
#pragma unroll
                for (int nt = 0; nt < NT; ++nt)
                    T[(size_t)row * DOUT + nt * 16 + lr] = f2bf(acc[m][nt][r] * ns);
            }
        }
    }
}

// ---------------------------------------------------------------- pull + fused finalize (TPN = D/8, ushort8 gathers)
template <int D>
__global__ __launch_bounds__(256) void pull_kernel(
    const u16* __restrict__ T, const u32* __restrict__ row_ptr,
    const u32* __restrict__ col, const float* __restrict__ norm_dst,
    const float* __restrict__ b, const float* __restrict__ sb,
    float* __restrict__ h) {
    constexpr int TPN = D / 8;
    int tid = blockIdx.x * 256 + threadIdx.x;
    int n = tid / TPN;
    int c = (tid % TPN) * 8;
    if (n >= N_NODES) return;

    u32 beg = row_ptr[n], end = row_ptr[n + 1];
    float a[8];
#pragma unroll
    for (int j = 0; j < 8; ++j) a[j] = 0.f;

    u32 e = beg;
    for (; e + 1 < end; e += 2) {
        u32 s0 = col[e], s1 = col[e + 1];
        uint4 q0 = *reinterpret_cast<const uint4*>(&T[s0 * D + c]);
        uint4 q1 = *reinterpret_cast<const uint4*>(&T[s1 * D + c]);
        a[0] += bflo(q0.x) + bflo(q1.x);
        a[1] += bfhi(q0.x) + bfhi(q1.x);
        a[2] += bflo(q0.y) + bflo(q1.y);
        a[3] += bfhi(q0.y) + bfhi(q1.y);
        a[4] += bflo(q0.z) + bflo(q1.z);
        a[5] += bfhi(q0.z) + bfhi(q1.z);
        a[6] += bflo(q0.w) + bflo(q1.w);
        a[7] += bfhi(q0.w) + bfhi(q1.w);
    }
    if (e < end) {
        uint4 q0 = *reinterpret_cast<const uint4*>(&T[col[e] * D + c]);
        a[0] += bflo(q0.x); a[1] += bfhi(q0.x);
        a[2] += bflo(q0.y); a[3] += bfhi(q0.y);
        a[4] += bflo(q0.z); a[5] += bfhi(q0.z);
        a[6] += bflo(q0.w); a[7] += bfhi(q0.w);
    }

    float nd = norm_dst[n];
    float sv = sb[0];
    float4 b0 = *reinterpret_cast<const float4*>(&b[c]);
    float4 b1 = *reinterpret_cast<const float4*>(&b[c + 4]);
    float4 o0, o1;
    o0.x = fmaxf(a[0] * nd + b0.x + sv, 0.f);
    o0.y = fmaxf(a[1] * nd + b0.y + sv, 0.f);
    o0.z = fmaxf(a[2] * nd + b0.z + sv, 0.f);
    o0.w = fmaxf(a[3] * nd + b0.w + sv, 0.f);
    o1.x = fmaxf(a[4] * nd + b1.x + sv, 0.f);
    o1.y = fmaxf(a[5] * nd + b1.y + sv, 0.f);
    o1.z = fmaxf(a[6] * nd + b1.z + sv, 0.f);
    o1.w = fmaxf(a[7] * nd + b1.w + sv, 0.f);
    *reinterpret_cast<float4*>(&h[n * D + c])     = o0;
    *reinterpret_cast<float4*>(&h[n * D + c + 4]) = o1;
}

// ---------------------------------------------------------------- last layer: pull + finalize + softmax -> f32 out
__global__ __launch_bounds__(256) void pull16_sm_kernel(
    const u16* __restrict__ T, const u32* __restrict__ row_ptr,
    const u32* __restrict__ col, const float* __restrict__ norm_dst,
    const float* __restrict__ b, const float* __restrict__ sb,
    float* __restrict__ out) {
    int tid = blockIdx.x * 256 + threadIdx.x;
    int n = tid >> 1;
    int c = (tid & 1) * 8;
    if (n >= N_NODES) return;

    u32 beg = row_ptr[n], end = row_ptr[n + 1];
    float a[8];
#pragma unroll
    for (int j = 0; j < 8; ++j) a[j] = 0.f;

    u32 e = beg;
    for (; e + 1 < end; e += 2) {
        u32 s0 = col[e], s1 = col[e + 1];
        uint4 q0 = *reinterpret_cast<const uint4*>(&T[s0 * 16 + c]);
        uint4 q1 = *reinterpret_cast<const uint4*>(&T[s1 * 16 + c]);
        a[0] += bflo(q0.x) + bflo(q1.x);
        a[1] += bfhi(q0.x) + bfhi(q1.x);
        a[2] += bflo(q0.y) + bflo(q1.y);
        a[3] += bfhi(q0.y) + bfhi(q1.y);
        a[4] += bflo(q0.z) + bflo(q1.z);
        a[5] += bfhi(q0.z) + bfhi(q1.z);
        a[6] += bflo(q0.w) + bflo(q1.w);
        a[7] += bfhi(q0.w) + bfhi(q1.w);
    }
    if (e < end) {
        uint4 q0 = *reinterpret_cast<const uint4*>(&T[col[e] * 16 + c]);
        a[0] += bflo(q0.x); a[1] += bfhi(q0.x);
        a[2] += bflo(q0.y); a[3] += bfhi(q0.y);
        a[4] += bflo(q0.z); a[5] += bfhi(q0.z);
        a[6] += bflo(q0.w); a[7] += bfhi(q0.w);
    }

    float nd = norm_dst[n];
    float sv = sb[0];
    float4 b0 = *reinterpret_cast<const float4*>(&b[c]);
    float4 b1 = *reinterpret_cast<const float4*>(&b[c + 4]);
    float o[8];
    o[0] = fmaxf(a[0] * nd + b0.x + sv, 0.f);
    o[1] = fmaxf(a[1] * nd + b0.y + sv, 0.f);
    o[2] = fmaxf(a[2] * nd + b0.z + sv, 0.f);
    o[3] = fmaxf(a[3] * nd + b0.w + sv, 0.f);
    o[4] = fmaxf(a[4] * nd + b1.x + sv, 0.f);
    o[5] = fmaxf(a[5] * nd + b1.y + sv, 0.f);
    o[6] = fmaxf(a[6] * nd + b1.z + sv, 0.f);
    o[7] = fmaxf(a[7] * nd + b1.w + sv, 0.f);

    float m = o[0];
#pragma unroll
    for (int j = 1; j < 8; ++j) m = fmaxf(m, o[j]);
    m = fmaxf(m, __shfl_xor(m, 1));
    float s = 0.f;
#pragma unroll
    for (int j = 0; j < 8; ++j) { o[j] = __expf(o[j] - m); s += o[j]; }
    s += __shfl_xor(s, 1);
    float inv = 1.f / s;
    float4 w0 = make_float4(o[0] * inv, o[1] * inv, o[2] * inv, o[3] * inv);
    float4 w1 = make_float4(o[4] * inv, o[5] * inv, o[6] * inv, o[7] * inv);
    *reinterpret_cast<float4*>(&out[n * 16 + c])     = w0;
    *reinterpret_cast<float4*>(&out[n * 16 + c + 4]) = w1;
}

// ---------------------------------------------------------------- launch
extern "C" void kernel_launch(void* const* d_in, const int* in_sizes, int n_in,
                              void* d_out, int out_size, void* d_ws, size_t ws_size,
                              hipStream_t stream) {
    const float* x   = (const float*)d_in[0];
    const int*   src = (const int*)d_in[1];
    const int*   dst = (const int*)d_in[2];
    const float* W0 = (const float*)d_in[3];
    const float* b0 = (const float*)d_in[4];
    const float* sb0 = (const float*)d_in[5];
    const float* W1 = (const float*)d_in[6];
    const float* b1 = (const float*)d_in[7];
    const float* sb1 = (const float*)d_in[8];
    const float* W2 = (const float*)d_in[9];
    const float* b2 = (const float*)d_in[10];
    const float* sb2 = (const float*)d_in[11];
    const float* W3 = (const float*)d_in[12];
    const float* b3 = (const float*)d_in[13];
    const float* sb3 = (const float*)d_in[14];

    // workspace layout (peak ~84.9 MB; proven-safe ≥85.6 MB):
    //   h      f32  N*128               @ 0
    //   T      bf16 N*128               @ 51.2M — during CSR build holds dslice/sslice
    //   col    u32  E                   @ 76.8M
    //   row_ptr u32 N+1                 @ 83.2M
    //   norm_src f32 N                  @ 83,600,016
    //   norm_dst f32 N                  @ 84,000,016
    //   bsum/boff u32                   @ 84,400,016
    //   indeg  u32 N                    @ 84,408,016
    //   wt     bf16 43520               @ 84,808,016  (pre-transposed W0..W3)
    char* ws = (char*)d_ws;
    float* h        = (float*)ws;
    u16*   T        = (u16*)(ws + 51200000);
    u32*   dslice   = (u32*)(ws + 51200000);
    u32*   sslice   = (u32*)(ws + 64000000);
    u32*   col      = (u32*)(ws + 76800000);
    u32*   row_ptr  = (u32*)(ws + 83200000);
    float* norm_src = (float*)(ws + 83600016);
    float* norm_dst = (float*)(ws + 84000016);
    u32*   bsum     = (u32*)(ws + 84400016);
    u32*   boff     = (u32*)(ws + 84404016);
    u32*   indeg    = (u32*)(ws + 84408016);
    u16*   wt       = (u16*)(ws + 84808016);

    const int NB = (N_NODES + 255) / 256;
    const int MT2 = (N_NODES + 127) / 128;   // 782 blocks, 128 rows each

    // ---- W prep + CSR build + norms
    wtprep_kernel<<<170, 256, 0, stream>>>(W0, W1, W2, W3, wt);
    hist_kernel<<<NRANGE * NSLICE, 256, 0, stream>>>(src, dst, dslice, sslice);
    prep_kernel<<<NB, 256, 0, stream>>>(dslice, sslice, indeg, norm_src, norm_dst);
    scan1_kernel<<<SCAN_NBLK, SCAN_B, 0, stream>>>(indeg, row_ptr, bsum);
    scan2_kernel<<<1, 256, 0, stream>>>(bsum, boff);
    scan3_kernel<<<NB, 256, 0, stream>>>(row_ptr, boff);
    fill2_kernel<<<NRANGE * NSLICE, 256, 0, stream>>>(src, dst, row_ptr, dslice, col);

    // ---- layer 0: 256 -> 128
    mgemm_kernel<256, 128><<<MT2, 256, 0, stream>>>(x, wt, norm_src, T);
    pull_kernel<128><<<(N_NODES * 16 + 255) / 256, 256, 0, stream>>>(T, row_ptr, col, norm_dst, b0, sb0, h);

    // ---- layer 1: 128 -> 64
    mgemm_kernel<128, 64><<<MT2, 256, 0, stream>>>(h, wt + 32768, norm_src, T);
    pull_kernel<64><<<(N_NODES * 8 + 255) / 256, 256, 0, stream>>>(T, row_ptr, col, norm_dst, b1, sb1, h);

    // ---- layer 2: 64 -> 32
    mgemm_kernel<64, 32><<<MT2, 256, 0, stream>>>(h, wt + 40960, norm_src, T);
    pull_kernel<32><<<(N_NODES * 4 + 255) / 256, 256, 0, stream>>>(T, row_ptr, col, norm_dst, b2, sb2, h);

    // ---- layer 3: 32 -> 16 + fused softmax -> f32 out
    mgemm_kernel<32, 16><<<MT2, 256, 0, stream>>>(h, wt + 43008, norm_src, T);
    pull16_sm_kernel<<<(N_NODES * 2 + 255) / 256, 256, 0, stream>>>(T, row_ptr, col, norm_dst, b3, sb3, (float*)d_out);
}